// Round 1
// baseline (3629.101 us; speedup 1.0000x reference)
//
#include <hip/hip_runtime.h>
#include <hip/hip_bf16.h>
#include <stdint.h>

#define BB 8
#define TT 1024
#define MM 8192
#define EE 1024
#define HH 128
#define SS (MM + TT)          // 9216
#define RKEEP (MM - 1024)     // 7168 rows kept after eviction
#define NSPLIT 4
#define SCHUNK (SS / NSPLIT)  // 2304

static __device__ __forceinline__ unsigned f2ord(float f) {
    unsigned u = __float_as_uint(f);
    return u ^ ((u & 0x80000000u) ? 0xFFFFFFFFu : 0x80000000u);
}
static __device__ __forceinline__ float ord2f(unsigned o) {
    unsigned u = (o & 0x80000000u) ? (o ^ 0x80000000u) : ~o;
    return __uint_as_float(u);
}

__device__ const float SCALEF = (float)(1.0 / 96.0);  // (M+T)^-0.5

// ---------------- K1: fused K,V projection over mk = [memory+posemb ; inp] ----
__global__ __launch_bounds__(256) void k_proj_kv(
    const float* __restrict__ memory, const int* __restrict__ mbd,
    const int* __restrict__ bpl, const float* __restrict__ pos_table,
    const float* __restrict__ inp, const float* __restrict__ Wk,
    const float* __restrict__ Wv, float* __restrict__ kO, float* __restrict__ vO)
{
    __shared__ float As[32][65];    // [e][row]
    __shared__ float Wks[32][129];  // [e][h]
    __shared__ float Wvs[32][129];
    const int tid = threadIdx.x;
    const int tx = tid & 15, ty = tid >> 4;
    const int b  = blockIdx.x / (SS / 64);
    const int s0 = (blockIdx.x % (SS / 64)) * 64;
    const bool reset = (bpl[b] == 0);

    float ak[4][8], av[4][8];
#pragma unroll
    for (int i = 0; i < 4; ++i)
#pragma unroll
        for (int j = 0; j < 8; ++j) { ak[i][j] = 0.f; av[i][j] = 0.f; }

    for (int e0 = 0; e0 < EE; e0 += 32) {
        for (int i = tid; i < 64 * 32; i += 256) {
            int row = i >> 5, e = i & 31;
            int s = s0 + row;
            float val;
            if (s < MM) {
                float mv = reset ? 0.f : memory[((size_t)b * MM + s) * EE + e0 + e];
                int d = reset ? 1 : (mbd[b * MM + s] + 1);
                int pix = 31 - __clz(d);  // exact floor(log2(d))
                val = mv + pos_table[pix * EE + e0 + e];
            } else {
                val = inp[((size_t)b * TT + (s - MM)) * EE + e0 + e];
            }
            As[e][row] = val;
        }
        for (int i = tid; i < 128 * 32; i += 256) {
            int h = i >> 5, e = i & 31;
            Wks[e][h] = Wk[h * EE + e0 + e];
            Wvs[e][h] = Wv[h * EE + e0 + e];
        }
        __syncthreads();
        for (int e = 0; e < 32; ++e) {
            float a[4], wk[8], wv[8];
#pragma unroll
            for (int i = 0; i < 4; ++i) a[i] = As[e][ty * 4 + i];
#pragma unroll
            for (int j = 0; j < 8; ++j) { wk[j] = Wks[e][tx * 8 + j]; wv[j] = Wvs[e][tx * 8 + j]; }
#pragma unroll
            for (int i = 0; i < 4; ++i)
#pragma unroll
                for (int j = 0; j < 8; ++j) {
                    ak[i][j] = fmaf(a[i], wk[j], ak[i][j]);
                    av[i][j] = fmaf(a[i], wv[j], av[i][j]);
                }
        }
        __syncthreads();
    }
#pragma unroll
    for (int i = 0; i < 4; ++i) {
        size_t base = ((size_t)b * SS + s0 + ty * 4 + i) * HH + tx * 8;
#pragma unroll
        for (int j = 0; j < 8; ++j) { kO[base + j] = ak[i][j]; vO[base + j] = av[i][j]; }
    }
}

// ---------------- K2: Q projection ----------------
__global__ __launch_bounds__(256) void k_proj_q(
    const float* __restrict__ inp, const float* __restrict__ Wq, float* __restrict__ qO)
{
    __shared__ float As[32][65];
    __shared__ float Wqs[32][129];
    const int tid = threadIdx.x;
    const int tx = tid & 15, ty = tid >> 4;
    const int b  = blockIdx.x / (TT / 64);
    const int t0 = (blockIdx.x % (TT / 64)) * 64;

    float aq[4][8];
#pragma unroll
    for (int i = 0; i < 4; ++i)
#pragma unroll
        for (int j = 0; j < 8; ++j) aq[i][j] = 0.f;

    for (int e0 = 0; e0 < EE; e0 += 32) {
        for (int i = tid; i < 64 * 32; i += 256) {
            int row = i >> 5, e = i & 31;
            As[e][row] = inp[((size_t)b * TT + t0 + row) * EE + e0 + e];
        }
        for (int i = tid; i < 128 * 32; i += 256) {
            int h = i >> 5, e = i & 31;
            Wqs[e][h] = Wq[h * EE + e0 + e];
        }
        __syncthreads();
        for (int e = 0; e < 32; ++e) {
            float a[4], wq[8];
#pragma unroll
            for (int i = 0; i < 4; ++i) a[i] = As[e][ty * 4 + i];
#pragma unroll
            for (int j = 0; j < 8; ++j) wq[j] = Wqs[e][tx * 8 + j];
#pragma unroll
            for (int i = 0; i < 4; ++i)
#pragma unroll
                for (int j = 0; j < 8; ++j) aq[i][j] = fmaf(a[i], wq[j], aq[i][j]);
        }
        __syncthreads();
    }
#pragma unroll
    for (int i = 0; i < 4; ++i) {
        size_t base = ((size_t)b * TT + t0 + ty * 4 + i) * HH + tx * 8;
#pragma unroll
        for (int j = 0; j < 8; ++j) qO[base + j] = aq[i][j];
    }
}

// ---------------- K3: rowmax of (qk*scale)^2 ----------------
__global__ __launch_bounds__(256) void k_rowmax(
    const float* __restrict__ q, const float* __restrict__ kM, float* __restrict__ rowmax)
{
    __shared__ float Qs[128][33];   // [h][row]
    __shared__ float Ks[32][132];   // [e][scol]
    __shared__ float Red[32][16];
    const int tid = threadIdx.x, tx = tid & 15, ty = tid >> 4;
    const int split = blockIdx.x & 3;
    const int tb = blockIdx.x >> 2;
    const int b  = tb >> 5;            // / (T/32)
    const int t0 = (tb & 31) * 32;

    for (int i = tid; i < 32 * 128; i += 256) {
        int h = i & 127, row = i >> 7;
        Qs[h][row] = q[((size_t)b * TT + t0 + row) * HH + h];
    }
    __syncthreads();

    float rmax[2] = {0.f, 0.f};
    const int sBeg = split * SCHUNK;
    for (int st = sBeg; st < sBeg + SCHUNK; st += 128) {
        float c[2][8] = {};
        for (int h0 = 0; h0 < 128; h0 += 32) {
            for (int i = tid; i < 128 * 32; i += 256) {
                int col = i >> 5, e = i & 31;
                Ks[e][col] = kM[((size_t)b * SS + st + col) * HH + h0 + e];
            }
            __syncthreads();
            for (int e = 0; e < 32; ++e) {
                float a0 = Qs[h0 + e][ty * 2], a1 = Qs[h0 + e][ty * 2 + 1];
                float kk[8];
#pragma unroll
                for (int j = 0; j < 8; ++j) kk[j] = Ks[e][tx * 8 + j];
#pragma unroll
                for (int j = 0; j < 8; ++j) {
                    c[0][j] = fmaf(a0, kk[j], c[0][j]);
                    c[1][j] = fmaf(a1, kk[j], c[1][j]);
                }
            }
            __syncthreads();
        }
#pragma unroll
        for (int i = 0; i < 2; ++i)
#pragma unroll
            for (int j = 0; j < 8; ++j) {
                float w = c[i][j] * SCALEF;
                float w2 = w * w;
                rmax[i] = fmaxf(rmax[i], w2);
            }
    }
    Red[ty * 2 + 0][tx] = rmax[0];
    Red[ty * 2 + 1][tx] = rmax[1];
    __syncthreads();
    if (tid < 32) {
        float m = Red[tid][0];
#pragma unroll
        for (int x = 1; x < 16; ++x) m = fmaxf(m, Red[tid][x]);
        atomicMax((int*)&rowmax[b * TT + t0 + tid], __float_as_int(m));  // all values >= 0
    }
}

// ---------------- K4: attention pass (wei, out, colsum, qt_loss) ----------------
__global__ __launch_bounds__(256) void k_attn(
    const float* __restrict__ q, const float* __restrict__ kM,
    const float* __restrict__ vM, const float* __restrict__ rowmax,
    float* __restrict__ outAcc, float* __restrict__ colsum, float* __restrict__ qtloss)
{
    __shared__ float Qs[128][33];
    __shared__ float KVs[32][132];
    __shared__ float Ws[128][33];   // wei [scol][row]
    __shared__ float qred[256];
    const int tid = threadIdx.x, tx = tid & 15, ty = tid >> 4;
    const int split = blockIdx.x & 3;
    const int tb = blockIdx.x >> 2;
    const int b  = tb >> 5;
    const int t0 = (tb & 31) * 32;

    for (int i = tid; i < 32 * 128; i += 256) {
        int h = i & 127, row = i >> 7;
        Qs[h][row] = q[((size_t)b * TT + t0 + row) * HH + h];
    }
    float rmx0 = rowmax[b * TT + t0 + ty * 2];
    float rmx1 = rowmax[b * TT + t0 + ty * 2 + 1];
    float oacc[2][8];
#pragma unroll
    for (int i = 0; i < 2; ++i)
#pragma unroll
        for (int j = 0; j < 8; ++j) oacc[i][j] = 0.f;
    float qtp = 0.f;
    __syncthreads();

    const int sBeg = split * SCHUNK;
    for (int st = sBeg; st < sBeg + SCHUNK; st += 128) {
        float c[2][8] = {};
        for (int h0 = 0; h0 < 128; h0 += 32) {
            for (int i = tid; i < 128 * 32; i += 256) {
                int col = i >> 5, e = i & 31;
                KVs[e][col] = kM[((size_t)b * SS + st + col) * HH + h0 + e];
            }
            __syncthreads();
            for (int e = 0; e < 32; ++e) {
                float a0 = Qs[h0 + e][ty * 2], a1 = Qs[h0 + e][ty * 2 + 1];
                float kk[8];
#pragma unroll
                for (int j = 0; j < 8; ++j) kk[j] = KVs[e][tx * 8 + j];
#pragma unroll
                for (int j = 0; j < 8; ++j) {
                    c[0][j] = fmaf(a0, kk[j], c[0][j]);   // identical order to k_rowmax
                    c[1][j] = fmaf(a1, kk[j], c[1][j]);
                }
            }
            __syncthreads();
        }
#pragma unroll
        for (int i = 0; i < 2; ++i) {
            float rmx = i ? rmx1 : rmx0;
#pragma unroll
            for (int j = 0; j < 8; ++j) {
                float w = c[i][j] * SCALEF;
                float w2 = w * w;
                float wei = w2 / rmx;
                qtp += logf(wei + 1e-4f);
                Ws[tx * 8 + j][ty * 2 + i] = wei;
            }
        }
        __syncthreads();
        if (tid < 128) {  // column sums over the 32 rows of this block
            float ssum = 0.f;
            for (int r = 0; r < 32; ++r) ssum += Ws[tid][r];
            atomicAdd(&colsum[b * SS + st + tid], ssum);
        }
        for (int ss = 0; ss < 128; ss += 32) {
            for (int i = tid; i < 32 * 128; i += 256) {
                int sl = i >> 7, h = i & 127;
                KVs[sl][h] = vM[((size_t)b * SS + st + ss + sl) * HH + h];
            }
            __syncthreads();
            for (int sl = 0; sl < 32; ++sl) {
                float w0 = Ws[ss + sl][ty * 2], w1 = Ws[ss + sl][ty * 2 + 1];
                float vv[8];
#pragma unroll
                for (int j = 0; j < 8; ++j) vv[j] = KVs[sl][tx * 8 + j];
#pragma unroll
                for (int j = 0; j < 8; ++j) {
                    oacc[0][j] = fmaf(w0, vv[j], oacc[0][j]);
                    oacc[1][j] = fmaf(w1, vv[j], oacc[1][j]);
                }
            }
            __syncthreads();
        }
    }
#pragma unroll
    for (int i = 0; i < 2; ++i)
#pragma unroll
        for (int j = 0; j < 8; ++j)
            atomicAdd(&outAcc[((size_t)b * TT + t0 + ty * 2 + i) * HH + tx * 8 + j], oacc[i][j]);

    qred[tid] = qtp;
    __syncthreads();
    for (int off = 128; off; off >>= 1) {
        if (tid < off) qred[tid] += qred[tid + off];
        __syncthreads();
    }
    if (tid == 0) atomicAdd(qtloss, qred[0]);
}

// ---------------- K5: rank + sortable keys ----------------
__global__ __launch_bounds__(256) void k_rank(
    const float* __restrict__ colsum, const float* __restrict__ mrank,
    unsigned long long* __restrict__ keys)
{
    const int b = blockIdx.x, tid = threadIdx.x;
    __shared__ float red[256];
    float p = 0.f;
    for (int s = tid; s < SS; s += 256) p += colsum[b * SS + s];
    red[tid] = p;
    __syncthreads();
    for (int off = 128; off; off >>= 1) {
        if (tid < off) red[tid] += red[tid + off];
        __syncthreads();
    }
    float mean = red[0] / (float)SS;
    for (int m = tid; m < MM; m += 256) {
        float rank = ((mrank[b * MM + m] + colsum[b * SS + m] / mean) - 1.0f) - 0.01f;
        keys[b * MM + m] = ((unsigned long long)(unsigned)(~f2ord(rank)) << 32) | (unsigned)m;
    }
}

// ---------------- K6: in-LDS bitonic sort (asc by key == desc by rank, idx tiebreak) ----
__global__ __launch_bounds__(1024) void k_sort(unsigned long long* __restrict__ keys)
{
    __shared__ unsigned long long a[MM];   // 64 KiB
    const int b = blockIdx.x, tid = threadIdx.x;
    for (int i = tid; i < MM; i += 1024) a[i] = keys[(size_t)b * MM + i];
    __syncthreads();
    for (int k = 2; k <= MM; k <<= 1) {
        for (int j = k >> 1; j > 0; j >>= 1) {
            for (int i = tid; i < MM; i += 1024) {
                int l = i ^ j;
                if (l > i) {
                    unsigned long long x = a[i], y = a[l];
                    bool up = ((i & k) == 0);
                    if ((x > y) == up) { a[i] = y; a[l] = x; }
                }
            }
            __syncthreads();
        }
    }
    for (int i = tid; i < MM; i += 1024) keys[(size_t)b * MM + i] = a[i];
}

// ---------------- K7: scatter sorted memory / dist / rank ----------------
__global__ __launch_bounds__(256) void k_scatter(
    const float* __restrict__ memory, const int* __restrict__ mbd,
    const int* __restrict__ bpl, const float* __restrict__ inp,
    const unsigned long long* __restrict__ keys,
    float* __restrict__ nmem, float* __restrict__ ndist, float* __restrict__ nrank)
{
    const int blk = blockIdx.x;
    const int b = blk >> 10;           // 1024 blocks per batch
    const int p0 = (blk & 1023) * 8;
    const bool reset = (bpl[b] == 0);
    const int tid = threadIdx.x;
    for (int r = 0; r < 8; ++r) {
        int p = p0 + r;
        float* drow = &nmem[((size_t)b * MM + p) * EE];
        if (p < RKEEP) {
            unsigned long long key = keys[(size_t)b * MM + p];
            int src = (int)(unsigned)(key & 0xFFFFFFFFu);
            const float* srow = &memory[((size_t)b * MM + src) * EE];
            for (int cc = tid; cc < EE; cc += 256) drow[cc] = reset ? 0.f : srow[cc];
            if (tid == 0) {
                ndist[b * MM + p] = reset ? 1.0f : (float)(mbd[b * MM + src] + 1);
                nrank[b * MM + p] = ord2f(~(unsigned)(key >> 32));
            }
        } else {
            int irow = p - RKEEP;
            const float* srow = &inp[((size_t)b * TT + irow) * EE];
            for (int cc = tid; cc < EE; cc += 256) drow[cc] = srow[cc];
            if (tid == 0) { ndist[b * MM + p] = 0.f; nrank[b * MM + p] = 1.0f; }
        }
    }
}

// ---------------- launcher ----------------
extern "C" void kernel_launch(void* const* d_in, const int* in_sizes, int n_in,
                              void* d_out, int out_size, void* d_ws, size_t ws_size,
                              hipStream_t stream)
{
    const int*   bpl    = (const int*)d_in[0];
    const float* inp    = (const float*)d_in[1];
    const float* memory = (const float*)d_in[2];
    const int*   mbd    = (const int*)d_in[3];
    const float* mrank  = (const float*)d_in[4];
    const float* pos    = (const float*)d_in[5];
    const float* Wk     = (const float*)d_in[6];
    const float* Wq     = (const float*)d_in[7];
    const float* Wv     = (const float*)d_in[8];

    float* out   = (float*)d_out;                    // [B,T,H]
    float* qtl   = out + (size_t)BB * TT * HH;       // scalar
    float* nmem  = qtl + 1;                          // [B,M,E]
    float* ndist = nmem + (size_t)BB * MM * EE;      // [B,M] (as float)
    float* nrank = ndist + (size_t)BB * MM;          // [B,M]

    char* w = (char*)d_ws;
    float* qb = (float*)w;  w += (size_t)BB * TT * HH * 4;
    float* kb = (float*)w;  w += (size_t)BB * SS * HH * 4;
    float* vb = (float*)w;  w += (size_t)BB * SS * HH * 4;
    float* rmax = (float*)w; w += (size_t)BB * TT * 4;
    float* csum = (float*)w; w += (size_t)BB * SS * 4;
    unsigned long long* keys = (unsigned long long*)w; w += (size_t)BB * MM * 8;
    if ((size_t)(w - (char*)d_ws) > ws_size) return;  // workspace too small: bail

    // zero accumulators (out region + qt_loss, rowmax + colsum are contiguous in ws)
    hipMemsetAsync(d_out, 0, ((size_t)BB * TT * HH + 1) * 4, stream);
    hipMemsetAsync(rmax, 0, ((size_t)BB * TT + (size_t)BB * SS) * 4, stream);

    k_proj_kv<<<BB * (SS / 64), 256, 0, stream>>>(memory, mbd, bpl, pos, inp, Wk, Wv, kb, vb);
    k_proj_q <<<BB * (TT / 64), 256, 0, stream>>>(inp, Wq, qb);
    k_rowmax <<<BB * (TT / 32) * NSPLIT, 256, 0, stream>>>(qb, kb, rmax);
    k_attn   <<<BB * (TT / 32) * NSPLIT, 256, 0, stream>>>(qb, kb, vb, rmax, out, csum, qtl);
    k_rank   <<<BB, 256, 0, stream>>>(csum, mrank, keys);
    k_sort   <<<BB, 1024, 0, stream>>>(keys);
    k_scatter<<<BB * (MM / 8), 256, 0, stream>>>(memory, mbd, bpl, inp, keys, nmem, ndist, nrank);
}

// Round 2
// 2120.770 us; speedup vs baseline: 1.7112x; 1.7112x over previous
//
#include <hip/hip_runtime.h>
#include <hip/hip_bf16.h>
#include <stdint.h>

#define BB 8
#define TT 1024
#define MM 8192
#define EE 1024
#define HH 128
#define SS (MM + TT)          // 9216
#define RKEEP (MM - 1024)     // 7168 rows kept after eviction
#define NSPLIT 4
#define SCHUNK (SS / NSPLIT)  // 2304
#define BK 32
#define LDW 40                // LDS row stride in shorts: 80B -> bank stride 20 (2-way max, free)

typedef __attribute__((ext_vector_type(8))) short bf16x8;
typedef __attribute__((ext_vector_type(4))) short s16x4;
typedef __attribute__((ext_vector_type(4))) float f32x4;

static __device__ __forceinline__ unsigned f2ord(float f) {
    unsigned u = __float_as_uint(f);
    return u ^ ((u & 0x80000000u) ? 0xFFFFFFFFu : 0x80000000u);
}
static __device__ __forceinline__ float ord2f(unsigned o) {
    unsigned u = (o & 0x80000000u) ? (o ^ 0x80000000u) : ~o;
    return __uint_as_float(u);
}
static __device__ __forceinline__ unsigned short f2bf(float x) {
    unsigned u = __float_as_uint(x);
    unsigned r = u + 0x7FFFu + ((u >> 16) & 1u);   // RNE (NaN not expected)
    return (unsigned short)(r >> 16);
}
static __device__ __forceinline__ float bf2f(unsigned short h) {
    return __uint_as_float(((unsigned)h) << 16);
}
// split x into hi+lo bf16
static __device__ __forceinline__ void bfsplit(float x, short& hi, short& lo) {
    unsigned short h = f2bf(x);
    hi = (short)h;
    lo = (short)f2bf(x - bf2f(h));
}

__device__ const float SCALEF = (float)(1.0 / 96.0);  // (M+T)^-0.5

// ---------------- K1: fused K,V projection via split-bf16 MFMA ----------------
// C[128 rows x 128 h] per block; A = mk rows (memory+posemb or inp), W = Wk/Wv [H][E].
__global__ __launch_bounds__(256) void k_proj_kv(
    const float* __restrict__ memory, const int* __restrict__ mbd,
    const int* __restrict__ bpl, const float* __restrict__ pos_table,
    const float* __restrict__ inp, const float* __restrict__ Wk,
    const float* __restrict__ Wv, float* __restrict__ kO, float* __restrict__ vO)
{
    __shared__ short Ah[128][LDW], Al[128][LDW];
    __shared__ short Bh[2][128][LDW], Bl[2][128][LDW];   // 0 = Wk, 1 = Wv
    const int tid = threadIdx.x;
    const int b   = blockIdx.y;
    const int s0  = blockIdx.x * 128;
    const bool reset = (bpl[b] == 0);
    const int lane = tid & 63, wid = tid >> 6;
    const int wr = wid >> 1, wc = wid & 1;       // 2x2 wave grid, 64x64 each
    const int fr = lane & 15, fq = lane >> 4;    // fragment row / k-quarter
    const int lrow = tid >> 3, lkq = tid & 7;    // staging: 32 rows x 8 quads per pass

    f32x4 accK[4][4], accV[4][4];
#pragma unroll
    for (int m = 0; m < 4; ++m)
#pragma unroll
        for (int n = 0; n < 4; ++n) {
            accK[m][n] = (f32x4){0.f, 0.f, 0.f, 0.f};
            accV[m][n] = (f32x4){0.f, 0.f, 0.f, 0.f};
        }

    for (int e0 = 0; e0 < EE; e0 += BK) {
        // ---- stage A tile (128 x 32 f32 -> hi/lo bf16) ----
#pragma unroll
        for (int p = 0; p < 4; ++p) {
            int row = p * 32 + lrow;
            int s = s0 + row;
            float x[4];
            if (s < MM) {
                int d = reset ? 1 : (mbd[b * MM + s] + 1);
                int pix = 31 - __clz(d);   // exact floor(log2(d))
                const float* pt = &pos_table[(size_t)pix * EE + e0 + lkq * 4];
                if (reset) {
                    x[0] = pt[0]; x[1] = pt[1]; x[2] = pt[2]; x[3] = pt[3];
                } else {
                    const float* mv = &memory[((size_t)b * MM + s) * EE + e0 + lkq * 4];
                    x[0] = mv[0] + pt[0]; x[1] = mv[1] + pt[1];
                    x[2] = mv[2] + pt[2]; x[3] = mv[3] + pt[3];
                }
            } else {
                const float* iv = &inp[((size_t)b * TT + (s - MM)) * EE + e0 + lkq * 4];
                x[0] = iv[0]; x[1] = iv[1]; x[2] = iv[2]; x[3] = iv[3];
            }
            s16x4 hi, lo;
#pragma unroll
            for (int c = 0; c < 4; ++c) { short h, l; bfsplit(x[c], h, l); hi[c] = h; lo[c] = l; }
            *(s16x4*)&Ah[row][lkq * 4] = hi;
            *(s16x4*)&Al[row][lkq * 4] = lo;
        }
        // ---- stage Wk / Wv tiles (128 x 32 each) ----
#pragma unroll
        for (int p = 0; p < 4; ++p) {
            int h = p * 32 + lrow;
            const float* wk = &Wk[(size_t)h * EE + e0 + lkq * 4];
            const float* wvp = &Wv[(size_t)h * EE + e0 + lkq * 4];
            s16x4 hi0, lo0, hi1, lo1;
#pragma unroll
            for (int c = 0; c < 4; ++c) {
                short hh, ll;
                bfsplit(wk[c], hh, ll);  hi0[c] = hh; lo0[c] = ll;
                bfsplit(wvp[c], hh, ll); hi1[c] = hh; lo1[c] = ll;
            }
            *(s16x4*)&Bh[0][h][lkq * 4] = hi0;
            *(s16x4*)&Bl[0][h][lkq * 4] = lo0;
            *(s16x4*)&Bh[1][h][lkq * 4] = hi1;
            *(s16x4*)&Bl[1][h][lkq * 4] = lo1;
        }
        __syncthreads();

        // ---- fragments + MFMA ----
        bf16x8 ah[4], al[4];
#pragma unroll
        for (int m = 0; m < 4; ++m) {
            int r = wr * 64 + m * 16 + fr;
            ah[m] = *(const bf16x8*)&Ah[r][fq * 8];
            al[m] = *(const bf16x8*)&Al[r][fq * 8];
        }
#pragma unroll
        for (int n = 0; n < 4; ++n) {
            int c = wc * 64 + n * 16 + fr;
            bf16x8 kh = *(const bf16x8*)&Bh[0][c][fq * 8];
            bf16x8 kl = *(const bf16x8*)&Bl[0][c][fq * 8];
            bf16x8 vh = *(const bf16x8*)&Bh[1][c][fq * 8];
            bf16x8 vl = *(const bf16x8*)&Bl[1][c][fq * 8];
#pragma unroll
            for (int m = 0; m < 4; ++m) {
                accK[m][n] = __builtin_amdgcn_mfma_f32_16x16x32_bf16(ah[m], kh, accK[m][n], 0, 0, 0);
                accK[m][n] = __builtin_amdgcn_mfma_f32_16x16x32_bf16(ah[m], kl, accK[m][n], 0, 0, 0);
                accK[m][n] = __builtin_amdgcn_mfma_f32_16x16x32_bf16(al[m], kh, accK[m][n], 0, 0, 0);
                accV[m][n] = __builtin_amdgcn_mfma_f32_16x16x32_bf16(ah[m], vh, accV[m][n], 0, 0, 0);
                accV[m][n] = __builtin_amdgcn_mfma_f32_16x16x32_bf16(ah[m], vl, accV[m][n], 0, 0, 0);
                accV[m][n] = __builtin_amdgcn_mfma_f32_16x16x32_bf16(al[m], vh, accV[m][n], 0, 0, 0);
            }
        }
        __syncthreads();
    }
    // ---- epilogue: D row=(lane>>4)*4+i (from A), col=lane&15 (from B) ----
#pragma unroll
    for (int m = 0; m < 4; ++m) {
        int row = s0 + wr * 64 + m * 16 + fq * 4;
#pragma unroll
        for (int n = 0; n < 4; ++n) {
            int col = wc * 64 + n * 16 + fr;
#pragma unroll
            for (int i = 0; i < 4; ++i) {
                size_t o = ((size_t)b * SS + row + i) * HH + col;
                kO[o] = accK[m][n][i];
                vO[o] = accV[m][n][i];
            }
        }
    }
}

// ---------------- K2: Q projection via split-bf16 MFMA ----------------
__global__ __launch_bounds__(256) void k_proj_q(
    const float* __restrict__ inp, const float* __restrict__ Wq, float* __restrict__ qO)
{
    __shared__ short Ah[128][LDW], Al[128][LDW];
    __shared__ short Bh[128][LDW], Bl[128][LDW];
    const int tid = threadIdx.x;
    const int b   = blockIdx.y;
    const int t0  = blockIdx.x * 128;
    const int lane = tid & 63, wid = tid >> 6;
    const int wr = wid >> 1, wc = wid & 1;
    const int fr = lane & 15, fq = lane >> 4;
    const int lrow = tid >> 3, lkq = tid & 7;

    f32x4 acc[4][4];
#pragma unroll
    for (int m = 0; m < 4; ++m)
#pragma unroll
        for (int n = 0; n < 4; ++n) acc[m][n] = (f32x4){0.f, 0.f, 0.f, 0.f};

    for (int e0 = 0; e0 < EE; e0 += BK) {
#pragma unroll
        for (int p = 0; p < 4; ++p) {
            int row = p * 32 + lrow;
            const float* iv = &inp[((size_t)b * TT + t0 + row) * EE + e0 + lkq * 4];
            const float* wq = &Wq[(size_t)(p * 32 + lrow) * EE + e0 + lkq * 4];
            s16x4 hiA, loA, hiB, loB;
#pragma unroll
            for (int c = 0; c < 4; ++c) {
                short h, l;
                bfsplit(iv[c], h, l); hiA[c] = h; loA[c] = l;
                bfsplit(wq[c], h, l); hiB[c] = h; loB[c] = l;
            }
            *(s16x4*)&Ah[row][lkq * 4] = hiA;
            *(s16x4*)&Al[row][lkq * 4] = loA;
            *(s16x4*)&Bh[row][lkq * 4] = hiB;
            *(s16x4*)&Bl[row][lkq * 4] = loB;
        }
        __syncthreads();
        bf16x8 ah[4], al[4];
#pragma unroll
        for (int m = 0; m < 4; ++m) {
            int r = wr * 64 + m * 16 + fr;
            ah[m] = *(const bf16x8*)&Ah[r][fq * 8];
            al[m] = *(const bf16x8*)&Al[r][fq * 8];
        }
#pragma unroll
        for (int n = 0; n < 4; ++n) {
            int c = wc * 64 + n * 16 + fr;
            bf16x8 bh = *(const bf16x8*)&Bh[c][fq * 8];
            bf16x8 bl = *(const bf16x8*)&Bl[c][fq * 8];
#pragma unroll
            for (int m = 0; m < 4; ++m) {
                acc[m][n] = __builtin_amdgcn_mfma_f32_16x16x32_bf16(ah[m], bh, acc[m][n], 0, 0, 0);
                acc[m][n] = __builtin_amdgcn_mfma_f32_16x16x32_bf16(ah[m], bl, acc[m][n], 0, 0, 0);
                acc[m][n] = __builtin_amdgcn_mfma_f32_16x16x32_bf16(al[m], bh, acc[m][n], 0, 0, 0);
            }
        }
        __syncthreads();
    }
#pragma unroll
    for (int m = 0; m < 4; ++m) {
        int row = t0 + wr * 64 + m * 16 + fq * 4;
#pragma unroll
        for (int n = 0; n < 4; ++n) {
            int col = wc * 64 + n * 16 + fr;
#pragma unroll
            for (int i = 0; i < 4; ++i)
                qO[((size_t)b * TT + row + i) * HH + col] = acc[m][n][i];
        }
    }
}

// ---------------- K3: rowmax of (qk*scale)^2 ----------------
__global__ __launch_bounds__(256) void k_rowmax(
    const float* __restrict__ q, const float* __restrict__ kM, float* __restrict__ rowmax)
{
    __shared__ float Qs[128][33];   // [h][row]
    __shared__ float Ks[32][132];   // [e][scol]
    __shared__ float Red[32][16];
    const int tid = threadIdx.x, tx = tid & 15, ty = tid >> 4;
    const int split = blockIdx.x & 3;
    const int tb = blockIdx.x >> 2;
    const int b  = tb >> 5;            // / (T/32)
    const int t0 = (tb & 31) * 32;

    for (int i = tid; i < 32 * 128; i += 256) {
        int h = i & 127, row = i >> 7;
        Qs[h][row] = q[((size_t)b * TT + t0 + row) * HH + h];
    }
    __syncthreads();

    float rmax[2] = {0.f, 0.f};
    const int sBeg = split * SCHUNK;
    for (int st = sBeg; st < sBeg + SCHUNK; st += 128) {
        float c[2][8] = {};
        for (int h0 = 0; h0 < 128; h0 += 32) {
            for (int i = tid; i < 128 * 32; i += 256) {
                int col = i >> 5, e = i & 31;
                Ks[e][col] = kM[((size_t)b * SS + st + col) * HH + h0 + e];
            }
            __syncthreads();
            for (int e = 0; e < 32; ++e) {
                float a0 = Qs[h0 + e][ty * 2], a1 = Qs[h0 + e][ty * 2 + 1];
                float kk[8];
#pragma unroll
                for (int j = 0; j < 8; ++j) kk[j] = Ks[e][tx * 8 + j];
#pragma unroll
                for (int j = 0; j < 8; ++j) {
                    c[0][j] = fmaf(a0, kk[j], c[0][j]);
                    c[1][j] = fmaf(a1, kk[j], c[1][j]);
                }
            }
            __syncthreads();
        }
#pragma unroll
        for (int i = 0; i < 2; ++i)
#pragma unroll
            for (int j = 0; j < 8; ++j) {
                float w = c[i][j] * SCALEF;
                float w2 = w * w;
                rmax[i] = fmaxf(rmax[i], w2);
            }
    }
    Red[ty * 2 + 0][tx] = rmax[0];
    Red[ty * 2 + 1][tx] = rmax[1];
    __syncthreads();
    if (tid < 32) {
        float m = Red[tid][0];
#pragma unroll
        for (int x = 1; x < 16; ++x) m = fmaxf(m, Red[tid][x]);
        atomicMax((int*)&rowmax[b * TT + t0 + tid], __float_as_int(m));  // all values >= 0
    }
}

// ---------------- K4: attention pass (wei, out, colsum, qt_loss) ----------------
__global__ __launch_bounds__(256) void k_attn(
    const float* __restrict__ q, const float* __restrict__ kM,
    const float* __restrict__ vM, const float* __restrict__ rowmax,
    float* __restrict__ outAcc, float* __restrict__ colsum, float* __restrict__ qtloss)
{
    __shared__ float Qs[128][33];
    __shared__ float KVs[32][132];
    __shared__ float Ws[128][33];   // wei [scol][row]
    __shared__ float qred[256];
    const int tid = threadIdx.x, tx = tid & 15, ty = tid >> 4;
    const int split = blockIdx.x & 3;
    const int tb = blockIdx.x >> 2;
    const int b  = tb >> 5;
    const int t0 = (tb & 31) * 32;

    for (int i = tid; i < 32 * 128; i += 256) {
        int h = i & 127, row = i >> 7;
        Qs[h][row] = q[((size_t)b * TT + t0 + row) * HH + h];
    }
    float rmx0 = rowmax[b * TT + t0 + ty * 2];
    float rmx1 = rowmax[b * TT + t0 + ty * 2 + 1];
    float oacc[2][8];
#pragma unroll
    for (int i = 0; i < 2; ++i)
#pragma unroll
        for (int j = 0; j < 8; ++j) oacc[i][j] = 0.f;
    float qtp = 0.f;
    __syncthreads();

    const int sBeg = split * SCHUNK;
    for (int st = sBeg; st < sBeg + SCHUNK; st += 128) {
        float c[2][8] = {};
        for (int h0 = 0; h0 < 128; h0 += 32) {
            for (int i = tid; i < 128 * 32; i += 256) {
                int col = i >> 5, e = i & 31;
                KVs[e][col] = kM[((size_t)b * SS + st + col) * HH + h0 + e];
            }
            __syncthreads();
            for (int e = 0; e < 32; ++e) {
                float a0 = Qs[h0 + e][ty * 2], a1 = Qs[h0 + e][ty * 2 + 1];
                float kk[8];
#pragma unroll
                for (int j = 0; j < 8; ++j) kk[j] = KVs[e][tx * 8 + j];
#pragma unroll
                for (int j = 0; j < 8; ++j) {
                    c[0][j] = fmaf(a0, kk[j], c[0][j]);   // identical order to k_rowmax
                    c[1][j] = fmaf(a1, kk[j], c[1][j]);
                }
            }
            __syncthreads();
        }
#pragma unroll
        for (int i = 0; i < 2; ++i) {
            float rmx = i ? rmx1 : rmx0;
#pragma unroll
            for (int j = 0; j < 8; ++j) {
                float w = c[i][j] * SCALEF;
                float w2 = w * w;
                float wei = w2 / rmx;
                qtp += logf(wei + 1e-4f);
                Ws[tx * 8 + j][ty * 2 + i] = wei;
            }
        }
        __syncthreads();
        if (tid < 128) {  // column sums over the 32 rows of this block
            float ssum = 0.f;
            for (int r = 0; r < 32; ++r) ssum += Ws[tid][r];
            atomicAdd(&colsum[b * SS + st + tid], ssum);
        }
        for (int ss = 0; ss < 128; ss += 32) {
            for (int i = tid; i < 32 * 128; i += 256) {
                int sl = i >> 7, h = i & 127;
                KVs[sl][h] = vM[((size_t)b * SS + st + ss + sl) * HH + h];
            }
            __syncthreads();
            for (int sl = 0; sl < 32; ++sl) {
                float w0 = Ws[ss + sl][ty * 2], w1 = Ws[ss + sl][ty * 2 + 1];
                float vv[8];
#pragma unroll
                for (int j = 0; j < 8; ++j) vv[j] = KVs[sl][tx * 8 + j];
#pragma unroll
                for (int j = 0; j < 8; ++j) {
                    oacc[0][j] = fmaf(w0, vv[j], oacc[0][j]);
                    oacc[1][j] = fmaf(w1, vv[j], oacc[1][j]);
                }
            }
            __syncthreads();
        }
    }
#pragma unroll
    for (int i = 0; i < 2; ++i)
#pragma unroll
        for (int j = 0; j < 8; ++j)
            atomicAdd(&outAcc[((size_t)b * TT + t0 + ty * 2 + i) * HH + tx * 8 + j], oacc[i][j]);

    qred[tid] = qtp;
    __syncthreads();
    for (int off = 128; off; off >>= 1) {
        if (tid < off) qred[tid] += qred[tid + off];
        __syncthreads();
    }
    if (tid == 0) atomicAdd(qtloss, qred[0]);
}

// ---------------- K5: rank + sortable keys ----------------
__global__ __launch_bounds__(256) void k_rank(
    const float* __restrict__ colsum, const float* __restrict__ mrank,
    unsigned long long* __restrict__ keys)
{
    const int b = blockIdx.x, tid = threadIdx.x;
    __shared__ float red[256];
    float p = 0.f;
    for (int s = tid; s < SS; s += 256) p += colsum[b * SS + s];
    red[tid] = p;
    __syncthreads();
    for (int off = 128; off; off >>= 1) {
        if (tid < off) red[tid] += red[tid + off];
        __syncthreads();
    }
    float mean = red[0] / (float)SS;
    for (int m = tid; m < MM; m += 256) {
        float rank = ((mrank[b * MM + m] + colsum[b * SS + m] / mean) - 1.0f) - 0.01f;
        keys[b * MM + m] = ((unsigned long long)(unsigned)(~f2ord(rank)) << 32) | (unsigned)m;
    }
}

// ---------------- K6: in-LDS bitonic sort (asc by key == desc by rank, idx tiebreak) ----
__global__ __launch_bounds__(1024) void k_sort(unsigned long long* __restrict__ keys)
{
    __shared__ unsigned long long a[MM];   // 64 KiB
    const int b = blockIdx.x, tid = threadIdx.x;
    for (int i = tid; i < MM; i += 1024) a[i] = keys[(size_t)b * MM + i];
    __syncthreads();
    for (int k = 2; k <= MM; k <<= 1) {
        for (int j = k >> 1; j > 0; j >>= 1) {
            for (int i = tid; i < MM; i += 1024) {
                int l = i ^ j;
                if (l > i) {
                    unsigned long long x = a[i], y = a[l];
                    bool up = ((i & k) == 0);
                    if ((x > y) == up) { a[i] = y; a[l] = x; }
                }
            }
            __syncthreads();
        }
    }
    for (int i = tid; i < MM; i += 1024) keys[(size_t)b * MM + i] = a[i];
}

// ---------------- K7: scatter sorted memory / dist / rank ----------------
__global__ __launch_bounds__(256) void k_scatter(
    const float* __restrict__ memory, const int* __restrict__ mbd,
    const int* __restrict__ bpl, const float* __restrict__ inp,
    const unsigned long long* __restrict__ keys,
    float* __restrict__ nmem, float* __restrict__ ndist, float* __restrict__ nrank)
{
    const int blk = blockIdx.x;
    const int b = blk >> 10;           // 1024 blocks per batch
    const int p0 = (blk & 1023) * 8;
    const bool reset = (bpl[b] == 0);
    const int tid = threadIdx.x;
    for (int r = 0; r < 8; ++r) {
        int p = p0 + r;
        float* drow = &nmem[((size_t)b * MM + p) * EE];
        if (p < RKEEP) {
            unsigned long long key = keys[(size_t)b * MM + p];
            int src = (int)(unsigned)(key & 0xFFFFFFFFu);
            const float* srow = &memory[((size_t)b * MM + src) * EE];
            for (int cc = tid; cc < EE; cc += 256) drow[cc] = reset ? 0.f : srow[cc];
            if (tid == 0) {
                ndist[b * MM + p] = reset ? 1.0f : (float)(mbd[b * MM + src] + 1);
                nrank[b * MM + p] = ord2f(~(unsigned)(key >> 32));
            }
        } else {
            int irow = p - RKEEP;
            const float* srow = &inp[((size_t)b * TT + irow) * EE];
            for (int cc = tid; cc < EE; cc += 256) drow[cc] = srow[cc];
            if (tid == 0) { ndist[b * MM + p] = 0.f; nrank[b * MM + p] = 1.0f; }
        }
    }
}

// ---------------- launcher ----------------
extern "C" void kernel_launch(void* const* d_in, const int* in_sizes, int n_in,
                              void* d_out, int out_size, void* d_ws, size_t ws_size,
                              hipStream_t stream)
{
    const int*   bpl    = (const int*)d_in[0];
    const float* inp    = (const float*)d_in[1];
    const float* memory = (const float*)d_in[2];
    const int*   mbd    = (const int*)d_in[3];
    const float* mrank  = (const float*)d_in[4];
    const float* pos    = (const float*)d_in[5];
    const float* Wk     = (const float*)d_in[6];
    const float* Wq     = (const float*)d_in[7];
    const float* Wv     = (const float*)d_in[8];

    float* out   = (float*)d_out;                    // [B,T,H]
    float* qtl   = out + (size_t)BB * TT * HH;       // scalar
    float* nmem  = qtl + 1;                          // [B,M,E]
    float* ndist = nmem + (size_t)BB * MM * EE;      // [B,M] (as float)
    float* nrank = ndist + (size_t)BB * MM;          // [B,M]

    char* w = (char*)d_ws;
    float* qb = (float*)w;  w += (size_t)BB * TT * HH * 4;
    float* kb = (float*)w;  w += (size_t)BB * SS * HH * 4;
    float* vb = (float*)w;  w += (size_t)BB * SS * HH * 4;
    float* rmax = (float*)w; w += (size_t)BB * TT * 4;
    float* csum = (float*)w; w += (size_t)BB * SS * 4;
    unsigned long long* keys = (unsigned long long*)w; w += (size_t)BB * MM * 8;
    if ((size_t)(w - (char*)d_ws) > ws_size) return;  // workspace too small: bail

    // zero accumulators (out region + qt_loss; rowmax + colsum contiguous in ws)
    hipMemsetAsync(d_out, 0, ((size_t)BB * TT * HH + 1) * 4, stream);
    hipMemsetAsync(rmax, 0, ((size_t)BB * TT + (size_t)BB * SS) * 4, stream);

    k_proj_kv<<<dim3(SS / 128, BB), 256, 0, stream>>>(memory, mbd, bpl, pos, inp, Wk, Wv, kb, vb);
    k_proj_q <<<dim3(TT / 128, BB), 256, 0, stream>>>(inp, Wq, qb);
    k_rowmax <<<BB * (TT / 32) * NSPLIT, 256, 0, stream>>>(qb, kb, rmax);
    k_attn   <<<BB * (TT / 32) * NSPLIT, 256, 0, stream>>>(qb, kb, vb, rmax, out, csum, qtl);
    k_rank   <<<BB, 256, 0, stream>>>(csum, mrank, keys);
    k_sort   <<<BB, 1024, 0, stream>>>(keys);
    k_scatter<<<BB * (MM / 8), 256, 0, stream>>>(memory, mbd, bpl, inp, keys, nmem, ndist, nrank);
}

// Round 3
// 985.070 us; speedup vs baseline: 3.6841x; 2.1529x over previous
//
#include <hip/hip_runtime.h>
#include <hip/hip_bf16.h>
#include <stdint.h>

#define BB 8
#define TT 1024
#define MM 8192
#define EE 1024
#define HH 128
#define SS (MM + TT)          // 9216
#define RKEEP (MM - 1024)     // 7168 rows kept after eviction
#define NSPLIT 8
#define SCHUNK (SS / NSPLIT)  // 1152
#define BK 32
#define LDW 40                // proj LDS row stride in shorts (80B)

typedef __attribute__((ext_vector_type(8))) short bf16x8;
typedef __attribute__((ext_vector_type(4))) short s16x4;
typedef __attribute__((ext_vector_type(4))) float f32x4;

static __device__ __forceinline__ unsigned f2ord(float f) {
    unsigned u = __float_as_uint(f);
    return u ^ ((u & 0x80000000u) ? 0xFFFFFFFFu : 0x80000000u);
}
static __device__ __forceinline__ float ord2f(unsigned o) {
    unsigned u = (o & 0x80000000u) ? (o ^ 0x80000000u) : ~o;
    return __uint_as_float(u);
}
static __device__ __forceinline__ unsigned short f2bf(float x) {
    unsigned u = __float_as_uint(x);
    unsigned r = u + 0x7FFFu + ((u >> 16) & 1u);   // RNE
    return (unsigned short)(r >> 16);
}
static __device__ __forceinline__ float bf2f(unsigned short h) {
    return __uint_as_float(((unsigned)h) << 16);
}
static __device__ __forceinline__ void bfsplit(float x, short& hi, short& lo) {
    unsigned short h = f2bf(x);
    hi = (short)h;
    lo = (short)f2bf(x - bf2f(h));
}

__device__ const float SCALEF = (float)(1.0 / 96.0);  // (M+T)^-0.5

// ---------------- K1: fused K,V projection; K -> hi/lo planes, V -> transposed hi/lo planes ----
__global__ __launch_bounds__(256) void k_proj_kv(
    const float* __restrict__ memory, const int* __restrict__ mbd,
    const int* __restrict__ bpl, const float* __restrict__ pos_table,
    const float* __restrict__ inp, const float* __restrict__ Wk,
    const float* __restrict__ Wv,
    short* __restrict__ kbh, short* __restrict__ kbl,
    short* __restrict__ vTh, short* __restrict__ vTl)
{
    __shared__ __align__(16) char smem_raw[61440];
    short* Ah  = (short*)smem_raw;        // [128][LDW]
    short* Al  = Ah  + 128 * LDW;
    short* Bh0 = Al  + 128 * LDW;
    short* Bl0 = Bh0 + 128 * LDW;
    short* Bh1 = Bl0 + 128 * LDW;
    short* Bl1 = Bh1 + 128 * LDW;
    float* tpT = (float*)smem_raw;        // epilogue: [64][132] f32 transpose tile

    const int tid = threadIdx.x;
    const int b   = blockIdx.y;
    const int s0  = blockIdx.x * 128;
    const bool reset = (bpl[b] == 0);
    const int lane = tid & 63, wid = tid >> 6;
    const int wr = wid >> 1, wc = wid & 1;
    const int fr = lane & 15, fq = lane >> 4;
    const int lrow = tid >> 3, lkq = tid & 7;

    f32x4 accK[4][4], accV[4][4];
#pragma unroll
    for (int m = 0; m < 4; ++m)
#pragma unroll
        for (int n = 0; n < 4; ++n) {
            accK[m][n] = (f32x4){0.f, 0.f, 0.f, 0.f};
            accV[m][n] = (f32x4){0.f, 0.f, 0.f, 0.f};
        }

    for (int e0 = 0; e0 < EE; e0 += BK) {
#pragma unroll
        for (int p = 0; p < 4; ++p) {
            int row = p * 32 + lrow;
            int s = s0 + row;
            float x[4];
            if (s < MM) {
                int d = reset ? 1 : (mbd[b * MM + s] + 1);
                int pix = 31 - __clz(d);
                const float* pt = &pos_table[(size_t)pix * EE + e0 + lkq * 4];
                if (reset) {
                    x[0] = pt[0]; x[1] = pt[1]; x[2] = pt[2]; x[3] = pt[3];
                } else {
                    const float* mv = &memory[((size_t)b * MM + s) * EE + e0 + lkq * 4];
                    x[0] = mv[0] + pt[0]; x[1] = mv[1] + pt[1];
                    x[2] = mv[2] + pt[2]; x[3] = mv[3] + pt[3];
                }
            } else {
                const float* iv = &inp[((size_t)b * TT + (s - MM)) * EE + e0 + lkq * 4];
                x[0] = iv[0]; x[1] = iv[1]; x[2] = iv[2]; x[3] = iv[3];
            }
            s16x4 hi, lo;
#pragma unroll
            for (int c = 0; c < 4; ++c) { short h, l; bfsplit(x[c], h, l); hi[c] = h; lo[c] = l; }
            *(s16x4*)&Ah[row * LDW + lkq * 4] = hi;
            *(s16x4*)&Al[row * LDW + lkq * 4] = lo;
        }
#pragma unroll
        for (int p = 0; p < 4; ++p) {
            int h = p * 32 + lrow;
            const float* wk  = &Wk[(size_t)h * EE + e0 + lkq * 4];
            const float* wvp = &Wv[(size_t)h * EE + e0 + lkq * 4];
            s16x4 hi0, lo0, hi1, lo1;
#pragma unroll
            for (int c = 0; c < 4; ++c) {
                short hh, ll;
                bfsplit(wk[c], hh, ll);  hi0[c] = hh; lo0[c] = ll;
                bfsplit(wvp[c], hh, ll); hi1[c] = hh; lo1[c] = ll;
            }
            *(s16x4*)&Bh0[h * LDW + lkq * 4] = hi0;
            *(s16x4*)&Bl0[h * LDW + lkq * 4] = lo0;
            *(s16x4*)&Bh1[h * LDW + lkq * 4] = hi1;
            *(s16x4*)&Bl1[h * LDW + lkq * 4] = lo1;
        }
        __syncthreads();

        bf16x8 ah[4], al[4];
#pragma unroll
        for (int m = 0; m < 4; ++m) {
            int r = wr * 64 + m * 16 + fr;
            ah[m] = *(const bf16x8*)&Ah[r * LDW + fq * 8];
            al[m] = *(const bf16x8*)&Al[r * LDW + fq * 8];
        }
#pragma unroll
        for (int n = 0; n < 4; ++n) {
            int c = wc * 64 + n * 16 + fr;
            bf16x8 kh = *(const bf16x8*)&Bh0[c * LDW + fq * 8];
            bf16x8 kl = *(const bf16x8*)&Bl0[c * LDW + fq * 8];
            bf16x8 vh = *(const bf16x8*)&Bh1[c * LDW + fq * 8];
            bf16x8 vl = *(const bf16x8*)&Bl1[c * LDW + fq * 8];
#pragma unroll
            for (int m = 0; m < 4; ++m) {
                accK[m][n] = __builtin_amdgcn_mfma_f32_16x16x32_bf16(ah[m], kh, accK[m][n], 0, 0, 0);
                accK[m][n] = __builtin_amdgcn_mfma_f32_16x16x32_bf16(ah[m], kl, accK[m][n], 0, 0, 0);
                accK[m][n] = __builtin_amdgcn_mfma_f32_16x16x32_bf16(al[m], kh, accK[m][n], 0, 0, 0);
                accV[m][n] = __builtin_amdgcn_mfma_f32_16x16x32_bf16(ah[m], vh, accV[m][n], 0, 0, 0);
                accV[m][n] = __builtin_amdgcn_mfma_f32_16x16x32_bf16(ah[m], vl, accV[m][n], 0, 0, 0);
                accV[m][n] = __builtin_amdgcn_mfma_f32_16x16x32_bf16(al[m], vh, accV[m][n], 0, 0, 0);
            }
        }
        __syncthreads();
    }

    // ---- K epilogue: split to hi/lo planes, layout [b][s][h] ----
#pragma unroll
    for (int m = 0; m < 4; ++m) {
        int row = s0 + wr * 64 + m * 16 + fq * 4;
#pragma unroll
        for (int n = 0; n < 4; ++n) {
            int col = wc * 64 + n * 16 + fr;
#pragma unroll
            for (int i = 0; i < 4; ++i) {
                short h, l; bfsplit(accK[m][n][i], h, l);
                size_t o = ((size_t)b * SS + row + i) * HH + col;
                kbh[o] = h; kbl[o] = l;
            }
        }
    }
    // ---- V epilogue: transpose via LDS, write [b][h][s] hi/lo planes ----
#pragma unroll
    for (int p = 0; p < 2; ++p) {
        __syncthreads();
        if (wc == p) {
#pragma unroll
            for (int m = 0; m < 4; ++m)
#pragma unroll
                for (int n = 0; n < 4; ++n) {
                    int col = n * 16 + fr;                 // local h (0..63)
                    int row = wr * 64 + m * 16 + fq * 4;   // s-local (0..124)
                    *(f32x4*)&tpT[col * 132 + row] = accV[m][n];
                }
        }
        __syncthreads();
        for (int idx = tid; idx < 64 * 32; idx += 256) {
            int h = idx >> 5, s4 = (idx & 31) << 2;
            f32x4 v = *(const f32x4*)&tpT[h * 132 + s4];
            s16x4 hi, lo;
#pragma unroll
            for (int j = 0; j < 4; ++j) { short hh, ll; bfsplit(v[j], hh, ll); hi[j] = hh; lo[j] = ll; }
            size_t o = ((size_t)b * HH + p * 64 + h) * SS + s0 + s4;
            *(s16x4*)&vTh[o] = hi;
            *(s16x4*)&vTl[o] = lo;
        }
    }
}

// ---------------- K2: Q projection -> hi/lo planes ----------------
__global__ __launch_bounds__(256) void k_proj_q(
    const float* __restrict__ inp, const float* __restrict__ Wq,
    short* __restrict__ qbh, short* __restrict__ qbl)
{
    __shared__ short Ah[128][LDW], Al[128][LDW];
    __shared__ short Bh[128][LDW], Bl[128][LDW];
    const int tid = threadIdx.x;
    const int b   = blockIdx.y;
    const int t0  = blockIdx.x * 128;
    const int lane = tid & 63, wid = tid >> 6;
    const int wr = wid >> 1, wc = wid & 1;
    const int fr = lane & 15, fq = lane >> 4;
    const int lrow = tid >> 3, lkq = tid & 7;

    f32x4 acc[4][4];
#pragma unroll
    for (int m = 0; m < 4; ++m)
#pragma unroll
        for (int n = 0; n < 4; ++n) acc[m][n] = (f32x4){0.f, 0.f, 0.f, 0.f};

    for (int e0 = 0; e0 < EE; e0 += BK) {
#pragma unroll
        for (int p = 0; p < 4; ++p) {
            int row = p * 32 + lrow;
            const float* iv = &inp[((size_t)b * TT + t0 + row) * EE + e0 + lkq * 4];
            const float* wq = &Wq[(size_t)(p * 32 + lrow) * EE + e0 + lkq * 4];
            s16x4 hiA, loA, hiB, loB;
#pragma unroll
            for (int c = 0; c < 4; ++c) {
                short h, l;
                bfsplit(iv[c], h, l); hiA[c] = h; loA[c] = l;
                bfsplit(wq[c], h, l); hiB[c] = h; loB[c] = l;
            }
            *(s16x4*)&Ah[row][lkq * 4] = hiA;
            *(s16x4*)&Al[row][lkq * 4] = loA;
            *(s16x4*)&Bh[row][lkq * 4] = hiB;
            *(s16x4*)&Bl[row][lkq * 4] = loB;
        }
        __syncthreads();
        bf16x8 ah[4], al[4];
#pragma unroll
        for (int m = 0; m < 4; ++m) {
            int r = wr * 64 + m * 16 + fr;
            ah[m] = *(const bf16x8*)&Ah[r][fq * 8];
            al[m] = *(const bf16x8*)&Al[r][fq * 8];
        }
#pragma unroll
        for (int n = 0; n < 4; ++n) {
            int c = wc * 64 + n * 16 + fr;
            bf16x8 bh = *(const bf16x8*)&Bh[c][fq * 8];
            bf16x8 bl = *(const bf16x8*)&Bl[c][fq * 8];
#pragma unroll
            for (int m = 0; m < 4; ++m) {
                acc[m][n] = __builtin_amdgcn_mfma_f32_16x16x32_bf16(ah[m], bh, acc[m][n], 0, 0, 0);
                acc[m][n] = __builtin_amdgcn_mfma_f32_16x16x32_bf16(ah[m], bl, acc[m][n], 0, 0, 0);
                acc[m][n] = __builtin_amdgcn_mfma_f32_16x16x32_bf16(al[m], bh, acc[m][n], 0, 0, 0);
            }
        }
        __syncthreads();
    }
#pragma unroll
    for (int m = 0; m < 4; ++m) {
        int row = t0 + wr * 64 + m * 16 + fq * 4;
#pragma unroll
        for (int n = 0; n < 4; ++n) {
            int col = wc * 64 + n * 16 + fr;
#pragma unroll
            for (int i = 0; i < 4; ++i) {
                short h, l; bfsplit(acc[m][n][i], h, l);
                size_t o = ((size_t)b * TT + row + i) * HH + col;
                qbh[o] = h; qbl[o] = l;
            }
        }
    }
}

// ---------------- shared attn helpers (MUST be identical in k_rowmax / k_attn) ----
__device__ __forceinline__ void stage_k64(const short* __restrict__ srcH, const short* __restrict__ srcL,
                                          size_t rowBase, int tid, short* sh, short* sl)
{
    for (int c = tid; c < 1024; c += 256) {
        int s = c >> 4, h8 = (c & 15) << 3;
        size_t g = (rowBase + s) * HH + h8;
        bf16x8 hv = *(const bf16x8*)&srcH[g];
        bf16x8 lv = *(const bf16x8*)&srcL[g];
        int sw = h8 ^ ((s & 7) << 3);
        *(bf16x8*)&sh[s * 128 + sw] = hv;
        *(bf16x8*)&sl[s * 128 + sw] = lv;
    }
}

__device__ __forceinline__ void load_qfrags(const short* __restrict__ qH, const short* __restrict__ qL,
                                            size_t rowIx, int fq, bf16x8 qh[4], bf16x8 ql[4])
{
    size_t base = rowIx * HH + fq * 8;
#pragma unroll
    for (int k = 0; k < 4; ++k) {
        qh[k] = *(const bf16x8*)&qH[base + k * 32];
        ql[k] = *(const bf16x8*)&qL[base + k * 32];
    }
}

__device__ __forceinline__ void qk_mfma4(const bf16x8 qh[4], const bf16x8 ql[4],
                                         const short* sh, const short* sl,
                                         int fr, int fq, f32x4 acc[4])
{
#pragma unroll
    for (int n = 0; n < 4; ++n) {
        int sc = n * 16 + fr;
        int ro = sc * 128, msk = (sc & 7) << 3;
#pragma unroll
        for (int k = 0; k < 4; ++k) {
            int off = ro + ((k * 32 + fq * 8) ^ msk);
            bf16x8 bh = *(const bf16x8*)&sh[off];
            bf16x8 bl = *(const bf16x8*)&sl[off];
            acc[n] = __builtin_amdgcn_mfma_f32_16x16x32_bf16(ql[k], bh, acc[n], 0, 0, 0);
            acc[n] = __builtin_amdgcn_mfma_f32_16x16x32_bf16(qh[k], bl, acc[n], 0, 0, 0);
            acc[n] = __builtin_amdgcn_mfma_f32_16x16x32_bf16(qh[k], bh, acc[n], 0, 0, 0);
        }
    }
}

// ---------------- K3: rowmax of (qk*scale)^2 via MFMA ----------------
__global__ __launch_bounds__(256) void k_rowmax(
    const short* __restrict__ qbh, const short* __restrict__ qbl,
    const short* __restrict__ kbh, const short* __restrict__ kbl,
    float* __restrict__ rowmax)
{
    __shared__ short Ksh[64 * 128], Ksl[64 * 128];
    const int tid = threadIdx.x, lane = tid & 63, wloc = tid >> 6;
    const int fr = lane & 15, fq = lane >> 4;
    const int split = blockIdx.x, t0 = blockIdx.y * 64, b = blockIdx.z;

    bf16x8 qh[4], ql[4];
    load_qfrags(qbh, qbl, (size_t)b * TT + t0 + wloc * 16 + fr, fq, qh, ql);

    float rm[4] = {0.f, 0.f, 0.f, 0.f};
    const int sBeg = split * SCHUNK;
    for (int st = sBeg; st < sBeg + SCHUNK; st += 64) {
        __syncthreads();
        stage_k64(kbh, kbl, (size_t)b * SS + st, tid, Ksh, Ksl);
        __syncthreads();
        f32x4 acc[4];
#pragma unroll
        for (int n = 0; n < 4; ++n) acc[n] = (f32x4){0.f, 0.f, 0.f, 0.f};
        qk_mfma4(qh, ql, Ksh, Ksl, fr, fq, acc);
#pragma unroll
        for (int n = 0; n < 4; ++n)
#pragma unroll
            for (int i = 0; i < 4; ++i) {
                float w = acc[n][i] * SCALEF;
                rm[i] = fmaxf(rm[i], w * w);
            }
    }
#pragma unroll
    for (int d = 1; d < 16; d <<= 1)
#pragma unroll
        for (int i = 0; i < 4; ++i)
            rm[i] = fmaxf(rm[i], __shfl_xor(rm[i], d, 64));
    if (fr == 0)
#pragma unroll
        for (int i = 0; i < 4; ++i)
            atomicMax((int*)&rowmax[b * TT + t0 + wloc * 16 + fq * 4 + i], __float_as_int(rm[i]));
}

// ---------------- K4: attention (wei, out, colsum-part, qt_loss) via MFMA ----------------
__global__ __launch_bounds__(256) void k_attn(
    const short* __restrict__ qbh, const short* __restrict__ qbl,
    const short* __restrict__ kbh, const short* __restrict__ kbl,
    const short* __restrict__ vTh, const short* __restrict__ vTl,
    const float* __restrict__ rowmax,
    float* __restrict__ outAcc, float* __restrict__ cpart, float* __restrict__ qtloss)
{
    __shared__ short Ksh[64 * 128], Ksl[64 * 128];   // reused as V^T [128][64]
    __shared__ short Ph[64 * 64], Pl[64 * 64];
    __shared__ float csLDS[SCHUNK];
    __shared__ float qred[256];
    const int tid = threadIdx.x, lane = tid & 63, wloc = tid >> 6;
    const int fr = lane & 15, fq = lane >> 4;
    const int split = blockIdx.x, t0 = blockIdx.y * 64, b = blockIdx.z;

    for (int i = tid; i < SCHUNK; i += 256) csLDS[i] = 0.f;

    bf16x8 qh[4], ql[4];
    load_qfrags(qbh, qbl, (size_t)b * TT + t0 + wloc * 16 + fr, fq, qh, ql);

    float inv[4];
#pragma unroll
    for (int i = 0; i < 4; ++i)
        inv[i] = 1.0f / rowmax[b * TT + t0 + wloc * 16 + fq * 4 + i];

    f32x4 oacc[8];
#pragma unroll
    for (int n = 0; n < 8; ++n) oacc[n] = (f32x4){0.f, 0.f, 0.f, 0.f};
    float qtp = 0.f;

    const int sBeg = split * SCHUNK;
    for (int st = sBeg; st < sBeg + SCHUNK; st += 64) {
        __syncthreads();
        stage_k64(kbh, kbl, (size_t)b * SS + st, tid, Ksh, Ksl);
        __syncthreads();
        f32x4 acc[4];
#pragma unroll
        for (int n = 0; n < 4; ++n) acc[n] = (f32x4){0.f, 0.f, 0.f, 0.f};
        qk_mfma4(qh, ql, Ksh, Ksl, fr, fq, acc);

#pragma unroll
        for (int n = 0; n < 4; ++n) {
            float cp = 0.f;
#pragma unroll
            for (int i = 0; i < 4; ++i) {
                float w = acc[n][i] * SCALEF;
                float w2 = w * w;
                float wei = w2 * inv[i];
                qtp += logf(wei + 1e-4f);
                cp += wei;
                short h, l; bfsplit(wei, h, l);
                int r = wloc * 16 + fq * 4 + i;
                int sw = (n * 16 + fr) ^ ((r & 7) << 3);
                Ph[r * 64 + sw] = h;
                Pl[r * 64 + sw] = l;
            }
            cp += __shfl_xor(cp, 16, 64);
            cp += __shfl_xor(cp, 32, 64);
            if (fq == 0) atomicAdd(&csLDS[st - sBeg + n * 16 + fr], cp);
        }
        __syncthreads();
        // stage V^T tile [128 h][64 s]
        for (int c = tid; c < 1024; c += 256) {
            int h = c >> 3, s8 = (c & 7) << 3;
            size_t g = ((size_t)b * HH + h) * SS + st + s8;
            bf16x8 hv = *(const bf16x8*)&vTh[g];
            bf16x8 lv = *(const bf16x8*)&vTl[g];
            int sw = s8 ^ ((h & 7) << 3);
            *(bf16x8*)&Ksh[h * 64 + sw] = hv;
            *(bf16x8*)&Ksl[h * 64 + sw] = lv;
        }
        __syncthreads();
        // PV
        {
            int rA = wloc * 16 + fr;
#pragma unroll
            for (int k = 0; k < 2; ++k) {
                int offA = rA * 64 + ((k * 32 + fq * 8) ^ ((rA & 7) << 3));
                bf16x8 ph = *(const bf16x8*)&Ph[offA];
                bf16x8 pl = *(const bf16x8*)&Pl[offA];
#pragma unroll
                for (int n = 0; n < 8; ++n) {
                    int hc = n * 16 + fr;
                    int offB = hc * 64 + ((k * 32 + fq * 8) ^ ((hc & 7) << 3));
                    bf16x8 vh = *(const bf16x8*)&Ksh[offB];
                    bf16x8 vl = *(const bf16x8*)&Ksl[offB];
                    oacc[n] = __builtin_amdgcn_mfma_f32_16x16x32_bf16(pl, vh, oacc[n], 0, 0, 0);
                    oacc[n] = __builtin_amdgcn_mfma_f32_16x16x32_bf16(ph, vl, oacc[n], 0, 0, 0);
                    oacc[n] = __builtin_amdgcn_mfma_f32_16x16x32_bf16(ph, vh, oacc[n], 0, 0, 0);
                }
            }
        }
    }

#pragma unroll
    for (int n = 0; n < 8; ++n)
#pragma unroll
        for (int i = 0; i < 4; ++i)
            atomicAdd(&outAcc[((size_t)b * TT + t0 + wloc * 16 + fq * 4 + i) * HH + n * 16 + fr],
                      oacc[n][i]);

    qred[tid] = qtp;
    __syncthreads();
    for (int off = 128; off; off >>= 1) {
        if (tid < off) qred[tid] += qred[tid + off];
        __syncthreads();
    }
    if (tid == 0) atomicAdd(qtloss, qred[0]);

    const int tt = blockIdx.y;
    for (int s = tid; s < SCHUNK; s += 256)
        cpart[((size_t)(b * 16 + tt)) * SS + sBeg + s] = csLDS[s];
}

// ---------------- K5: rank + sortable keys (deterministic colsum reduce) ----------------
__global__ __launch_bounds__(256) void k_rank(
    const float* __restrict__ cpart, const float* __restrict__ mrank,
    unsigned long long* __restrict__ keys, float* __restrict__ csum)
{
    const int b = blockIdx.x, tid = threadIdx.x;
    __shared__ float red[256];
    float p = 0.f;
    for (int s = tid; s < SS; s += 256) {
        float cs = 0.f;
#pragma unroll
        for (int tt = 0; tt < 16; ++tt) cs += cpart[((size_t)(b * 16 + tt)) * SS + s];
        csum[b * SS + s] = cs;
        p += cs;
    }
    red[tid] = p;
    __syncthreads();
    for (int off = 128; off; off >>= 1) {
        if (tid < off) red[tid] += red[tid + off];
        __syncthreads();
    }
    float mean = red[0] / (float)SS;
    for (int m = tid; m < MM; m += 256) {
        float rank = ((mrank[b * MM + m] + csum[b * SS + m] / mean) - 1.0f) - 0.01f;
        keys[b * MM + m] = ((unsigned long long)(unsigned)(~f2ord(rank)) << 32) | (unsigned)m;
    }
}

// ---------------- K6: in-LDS bitonic sort ----------------
__global__ __launch_bounds__(1024) void k_sort(unsigned long long* __restrict__ keys)
{
    __shared__ unsigned long long a[MM];
    const int b = blockIdx.x, tid = threadIdx.x;
    for (int i = tid; i < MM; i += 1024) a[i] = keys[(size_t)b * MM + i];
    __syncthreads();
    for (int k = 2; k <= MM; k <<= 1) {
        for (int j = k >> 1; j > 0; j >>= 1) {
            for (int i = tid; i < MM; i += 1024) {
                int l = i ^ j;
                if (l > i) {
                    unsigned long long x = a[i], y = a[l];
                    bool up = ((i & k) == 0);
                    if ((x > y) == up) { a[i] = y; a[l] = x; }
                }
            }
            __syncthreads();
        }
    }
    for (int i = tid; i < MM; i += 1024) keys[(size_t)b * MM + i] = a[i];
}

// ---------------- K7: scatter sorted memory / dist / rank ----------------
__global__ __launch_bounds__(256) void k_scatter(
    const float* __restrict__ memory, const int* __restrict__ mbd,
    const int* __restrict__ bpl, const float* __restrict__ inp,
    const unsigned long long* __restrict__ keys,
    float* __restrict__ nmem, float* __restrict__ ndist, float* __restrict__ nrank)
{
    const int blk = blockIdx.x;
    const int b = blk >> 10;
    const int p0 = (blk & 1023) * 8;
    const bool reset = (bpl[b] == 0);
    const int tid = threadIdx.x;
    const f32x4 zero = (f32x4){0.f, 0.f, 0.f, 0.f};
    for (int r = 0; r < 8; ++r) {
        int p = p0 + r;
        float* drow = &nmem[((size_t)b * MM + p) * EE];
        if (p < RKEEP) {
            unsigned long long key = keys[(size_t)b * MM + p];
            int src = (int)(unsigned)(key & 0xFFFFFFFFu);
            const float* srow = &memory[((size_t)b * MM + src) * EE];
            *(f32x4*)&drow[tid * 4] = reset ? zero : *(const f32x4*)&srow[tid * 4];
            if (tid == 0) {
                ndist[b * MM + p] = reset ? 1.0f : (float)(mbd[b * MM + src] + 1);
                nrank[b * MM + p] = ord2f(~(unsigned)(key >> 32));
            }
        } else {
            int irow = p - RKEEP;
            const float* srow = &inp[((size_t)b * TT + irow) * EE];
            *(f32x4*)&drow[tid * 4] = *(const f32x4*)&srow[tid * 4];
            if (tid == 0) { ndist[b * MM + p] = 0.f; nrank[b * MM + p] = 1.0f; }
        }
    }
}

// ---------------- launcher ----------------
extern "C" void kernel_launch(void* const* d_in, const int* in_sizes, int n_in,
                              void* d_out, int out_size, void* d_ws, size_t ws_size,
                              hipStream_t stream)
{
    const int*   bpl    = (const int*)d_in[0];
    const float* inp    = (const float*)d_in[1];
    const float* memory = (const float*)d_in[2];
    const int*   mbd    = (const int*)d_in[3];
    const float* mrank  = (const float*)d_in[4];
    const float* pos    = (const float*)d_in[5];
    const float* Wk     = (const float*)d_in[6];
    const float* Wq     = (const float*)d_in[7];
    const float* Wv     = (const float*)d_in[8];

    float* out   = (float*)d_out;                    // [B,T,H]
    float* qtl   = out + (size_t)BB * TT * HH;       // scalar
    float* nmem  = qtl + 1;                          // [B,M,E]
    float* ndist = nmem + (size_t)BB * MM * EE;      // [B,M]
    float* nrank = ndist + (size_t)BB * MM;          // [B,M]

    char* w = (char*)d_ws;
    short* qbh = (short*)w; w += (size_t)BB * TT * HH * 2;
    short* qbl = (short*)w; w += (size_t)BB * TT * HH * 2;
    short* kbh = (short*)w; w += (size_t)BB * SS * HH * 2;
    short* kbl = (short*)w; w += (size_t)BB * SS * HH * 2;
    short* vTh = (short*)w; w += (size_t)BB * HH * SS * 2;
    short* vTl = (short*)w; w += (size_t)BB * HH * SS * 2;
    float* rmax = (float*)w; w += (size_t)BB * TT * 4;
    float* csum = (float*)w; w += (size_t)BB * SS * 4;
    float* cpart = (float*)w; w += (size_t)BB * 16 * SS * 4;
    unsigned long long* keys = (unsigned long long*)w; w += (size_t)BB * MM * 8;
    if ((size_t)(w - (char*)d_ws) > ws_size) return;

    hipMemsetAsync(d_out, 0, ((size_t)BB * TT * HH + 1) * 4, stream);
    hipMemsetAsync(rmax, 0, (size_t)BB * TT * 4, stream);

    k_proj_kv<<<dim3(SS / 128, BB), 256, 0, stream>>>(memory, mbd, bpl, pos, inp, Wk, Wv,
                                                      kbh, kbl, vTh, vTl);
    k_proj_q <<<dim3(TT / 128, BB), 256, 0, stream>>>(inp, Wq, qbh, qbl);
    k_rowmax <<<dim3(NSPLIT, TT / 64, BB), 256, 0, stream>>>(qbh, qbl, kbh, kbl, rmax);
    k_attn   <<<dim3(NSPLIT, TT / 64, BB), 256, 0, stream>>>(qbh, qbl, kbh, kbl, vTh, vTl,
                                                             rmax, out, cpart, qtl);
    k_rank   <<<BB, 256, 0, stream>>>(cpart, mrank, keys, csum);
    k_sort   <<<BB, 1024, 0, stream>>>(keys);
    k_scatter<<<BB * (MM / 8), 256, 0, stream>>>(memory, mbd, bpl, inp, keys, nmem, ndist, nrank);
}

// Round 4
// 950.525 us; speedup vs baseline: 3.8180x; 1.0363x over previous
//
#include <hip/hip_runtime.h>
#include <hip/hip_bf16.h>
#include <stdint.h>

#define BB 8
#define TT 1024
#define MM 8192
#define EE 1024
#define HH 128
#define SS (MM + TT)          // 9216
#define RKEEP (MM - 1024)     // 7168 rows kept after eviction
#define NSPLIT 8
#define SCHUNK (SS / NSPLIT)  // 1152
#define BK 32
#define LDW 40                // A-tile LDS row stride in shorts (80B, conflict-benign)

typedef __attribute__((ext_vector_type(8))) short bf16x8;
typedef __attribute__((ext_vector_type(4))) short s16x4;
typedef __attribute__((ext_vector_type(4))) float f32x4;

static __device__ __forceinline__ unsigned f2ord(float f) {
    unsigned u = __float_as_uint(f);
    return u ^ ((u & 0x80000000u) ? 0xFFFFFFFFu : 0x80000000u);
}
static __device__ __forceinline__ float ord2f(unsigned o) {
    unsigned u = (o & 0x80000000u) ? (o ^ 0x80000000u) : ~o;
    return __uint_as_float(u);
}
static __device__ __forceinline__ unsigned short f2bf(float x) {
    unsigned u = __float_as_uint(x);
    unsigned r = u + 0x7FFFu + ((u >> 16) & 1u);   // RNE
    return (unsigned short)(r >> 16);
}
static __device__ __forceinline__ float bf2f(unsigned short h) {
    return __uint_as_float(((unsigned)h) << 16);
}
static __device__ __forceinline__ void bfsplit(float x, short& hi, short& lo) {
    unsigned short h = f2bf(x);
    hi = (short)h;
    lo = (short)f2bf(x - bf2f(h));
}

// async global->LDS, 16B per lane; dest = wave-uniform base + lane*16
static __device__ __forceinline__ void gload_lds16(const short* g, short* l) {
    __builtin_amdgcn_global_load_lds(
        (const __attribute__((address_space(1))) void*)g,
        (__attribute__((address_space(3))) void*)l, 16, 0, 0);
}

__device__ const float SCALEF = (float)(1.0 / 96.0);  // (M+T)^-0.5

// ---------------- K0: pre-split weights into hi/lo bf16 planes ----------------
__global__ __launch_bounds__(256) void k_wsplit(
    const float* __restrict__ Wk, const float* __restrict__ Wq, const float* __restrict__ Wv,
    short* __restrict__ wkh, short* __restrict__ wkl,
    short* __restrict__ wqh, short* __restrict__ wql,
    short* __restrict__ wvh, short* __restrict__ wvl)
{
    int idx = blockIdx.x * 256 + threadIdx.x;     // 3 * 32768 threads, 4 elems each
    int m = idx >> 15;
    int o4 = (idx & 32767) * 4;
    const float* W = m == 0 ? Wk : (m == 1 ? Wq : Wv);
    short* dh = m == 0 ? wkh : (m == 1 ? wqh : wvh);
    short* dl = m == 0 ? wkl : (m == 1 ? wql : wvl);
    f32x4 v = *(const f32x4*)&W[o4];
    s16x4 hi, lo;
#pragma unroll
    for (int j = 0; j < 4; ++j) { short h, l; bfsplit(v[j], h, l); hi[j] = h; lo[j] = l; }
    *(s16x4*)&dh[o4] = hi;
    *(s16x4*)&dl[o4] = lo;
}

// ---------------- K1: fused K,V projection ----------------
__global__ __launch_bounds__(256) void k_proj_kv(
    const float* __restrict__ memory, const int* __restrict__ mbd,
    const int* __restrict__ bpl, const float* __restrict__ pos_table,
    const float* __restrict__ inp,
    const short* __restrict__ wkh, const short* __restrict__ wkl,
    const short* __restrict__ wvh, const short* __restrict__ wvl,
    short* __restrict__ kbh, short* __restrict__ kbl,
    short* __restrict__ vTh, short* __restrict__ vTl)
{
    __shared__ __align__(16) short smA[2][128 * LDW];   // Ah, Al (20KB)
    __shared__ __align__(16) short smB[4][128 * 32];    // kh,kl,vh,vl (32KB), swizzled

    const int tid = threadIdx.x;
    const int b   = blockIdx.y;
    const int s0  = blockIdx.x * 128;
    const bool reset = (bpl[b] == 0);
    const int lane = tid & 63, wid = tid >> 6;
    const int wr = wid >> 1, wc = wid & 1;
    const int fr = lane & 15, fq = lane >> 4;
    const int lrow = tid >> 3, lkq = tid & 7;

    // per-thread A-row metadata (constant over K-loop)
    int pixr[4];
    const float* aptr[4];
#pragma unroll
    for (int p = 0; p < 4; ++p) {
        int s = s0 + p * 32 + lrow;
        if (s < MM) {
            int d = reset ? 1 : (mbd[b * MM + s] + 1);
            pixr[p] = 31 - __clz(d);
            aptr[p] = reset ? nullptr : &memory[((size_t)b * MM + s) * EE];
        } else {
            pixr[p] = -1;
            aptr[p] = &inp[((size_t)b * TT + (s - MM)) * EE];
        }
    }

    f32x4 accK[4][4], accV[4][4];
#pragma unroll
    for (int m = 0; m < 4; ++m)
#pragma unroll
        for (int n = 0; n < 4; ++n) {
            accK[m][n] = (f32x4){0.f, 0.f, 0.f, 0.f};
            accV[m][n] = (f32x4){0.f, 0.f, 0.f, 0.f};
        }

    // staging helpers
    const int wh  = (tid >> 2);           // 0..63 (W row within 64-row pass)
    const int wk8 = (tid & 3) * 8;        // dest col group
    const int wdst = (tid >> 6) * 512;    // wave-uniform LDS base (shorts) within plane pass

#define STAGEW(e0_)                                                            \
    {                                                                          \
        _Pragma("unroll")                                                      \
        for (int p = 0; p < 2; ++p) {                                          \
            int h = p * 64 + wh;                                               \
            int ec = wk8 ^ ((h & 3) << 3);                                     \
            size_t g = (size_t)h * EE + (e0_) + ec;                            \
            gload_lds16(&wkh[g], &smB[0][p * 2048 + wdst]);                    \
            gload_lds16(&wkl[g], &smB[1][p * 2048 + wdst]);                    \
            gload_lds16(&wvh[g], &smB[2][p * 2048 + wdst]);                    \
            gload_lds16(&wvl[g], &smB[3][p * 2048 + wdst]);                    \
        }                                                                      \
    }

    auto LOADA = [&](int e0, f32x4 xa[4]) {
#pragma unroll
        for (int p = 0; p < 4; ++p) {
            f32x4 v = (f32x4){0.f, 0.f, 0.f, 0.f};
            if (aptr[p]) v = *(const f32x4*)&aptr[p][e0 + lkq * 4];
            if (pixr[p] >= 0) {
                f32x4 pt = *(const f32x4*)&pos_table[(size_t)pixr[p] * EE + e0 + lkq * 4];
                v[0] += pt[0]; v[1] += pt[1]; v[2] += pt[2]; v[3] += pt[3];
            }
            xa[p] = v;
        }
    };
    auto STOREA = [&](const f32x4 xa[4]) {
#pragma unroll
        for (int p = 0; p < 4; ++p) {
            int row = p * 32 + lrow;
            s16x4 hi, lo;
#pragma unroll
            for (int c = 0; c < 4; ++c) { short h, l; bfsplit(xa[p][c], h, l); hi[c] = h; lo[c] = l; }
            *(s16x4*)&smA[0][row * LDW + lkq * 4] = hi;
            *(s16x4*)&smA[1][row * LDW + lkq * 4] = lo;
        }
    };

    f32x4 xa[4];
    LOADA(0, xa);
    STOREA(xa);
    STAGEW(0);
    __syncthreads();

    for (int step = 0; step < 32; ++step) {
        if (step < 31) LOADA((step + 1) * BK, xa);   // prefetch next A tile into regs

        bf16x8 ah[4], al[4];
#pragma unroll
        for (int m = 0; m < 4; ++m) {
            int r = wr * 64 + m * 16 + fr;
            ah[m] = *(const bf16x8*)&smA[0][r * LDW + fq * 8];
            al[m] = *(const bf16x8*)&smA[1][r * LDW + fq * 8];
        }
#pragma unroll
        for (int n = 0; n < 4; ++n) {
            int c = wc * 64 + n * 16 + fr;
            int off = c * 32 + ((fq * 8) ^ ((c & 3) << 3));
            bf16x8 kh = *(const bf16x8*)&smB[0][off];
            bf16x8 kl = *(const bf16x8*)&smB[1][off];
            bf16x8 vh = *(const bf16x8*)&smB[2][off];
            bf16x8 vl = *(const bf16x8*)&smB[3][off];
#pragma unroll
            for (int m = 0; m < 4; ++m) {
                accK[m][n] = __builtin_amdgcn_mfma_f32_16x16x32_bf16(ah[m], kh, accK[m][n], 0, 0, 0);
                accK[m][n] = __builtin_amdgcn_mfma_f32_16x16x32_bf16(ah[m], kl, accK[m][n], 0, 0, 0);
                accK[m][n] = __builtin_amdgcn_mfma_f32_16x16x32_bf16(al[m], kh, accK[m][n], 0, 0, 0);
                accV[m][n] = __builtin_amdgcn_mfma_f32_16x16x32_bf16(ah[m], vh, accV[m][n], 0, 0, 0);
                accV[m][n] = __builtin_amdgcn_mfma_f32_16x16x32_bf16(ah[m], vl, accV[m][n], 0, 0, 0);
                accV[m][n] = __builtin_amdgcn_mfma_f32_16x16x32_bf16(al[m], vh, accV[m][n], 0, 0, 0);
            }
        }
        __syncthreads();
        if (step < 31) {
            STOREA(xa);
            STAGEW((step + 1) * BK);
            __syncthreads();
        }
    }

    // ---- K epilogue ----
#pragma unroll
    for (int m = 0; m < 4; ++m) {
        int row = s0 + wr * 64 + m * 16 + fq * 4;
#pragma unroll
        for (int n = 0; n < 4; ++n) {
            int col = wc * 64 + n * 16 + fr;
#pragma unroll
            for (int i = 0; i < 4; ++i) {
                short h, l; bfsplit(accK[m][n][i], h, l);
                size_t o = ((size_t)b * SS + row + i) * HH + col;
                kbh[o] = h; kbl[o] = l;
            }
        }
    }
    // ---- V epilogue: transpose via LDS (32-col passes aliasing smB), write [b][h][s] ----
    float* tpT = (float*)smB;   // [32][132] f32 = 16.9KB <= 32KB
#pragma unroll
    for (int p = 0; p < 2; ++p)
#pragma unroll
        for (int half = 0; half < 2; ++half) {
            __syncthreads();
            if (wc == p) {
#pragma unroll
                for (int m = 0; m < 4; ++m)
#pragma unroll
                    for (int n2 = 0; n2 < 2; ++n2) {
                        int n = half * 2 + n2;
                        int cl = n2 * 16 + fr;
                        int row = wr * 64 + m * 16 + fq * 4;
                        *(f32x4*)&tpT[cl * 132 + row] = accV[m][n];
                    }
            }
            __syncthreads();
            for (int idx = tid; idx < 32 * 32; idx += 256) {
                int hcl = idx >> 5, s4 = (idx & 31) << 2;
                f32x4 v = *(const f32x4*)&tpT[hcl * 132 + s4];
                s16x4 hi, lo;
#pragma unroll
                for (int j = 0; j < 4; ++j) { short hh, ll; bfsplit(v[j], hh, ll); hi[j] = hh; lo[j] = ll; }
                size_t o = ((size_t)b * HH + p * 64 + half * 32 + hcl) * SS + s0 + s4;
                *(s16x4*)&vTh[o] = hi;
                *(s16x4*)&vTl[o] = lo;
            }
        }
}

// ---------------- K2: Q projection ----------------
__global__ __launch_bounds__(256) void k_proj_q(
    const float* __restrict__ inp,
    const short* __restrict__ wqh, const short* __restrict__ wql,
    short* __restrict__ qbh, short* __restrict__ qbl)
{
    __shared__ __align__(16) short smA[2][128 * LDW];
    __shared__ __align__(16) short smB[2][128 * 32];
    const int tid = threadIdx.x;
    const int b   = blockIdx.y;
    const int t0  = blockIdx.x * 128;
    const int lane = tid & 63, wid = tid >> 6;
    const int wr = wid >> 1, wc = wid & 1;
    const int fr = lane & 15, fq = lane >> 4;
    const int lrow = tid >> 3, lkq = tid & 7;
    const int wh  = (tid >> 2);
    const int wk8 = (tid & 3) * 8;
    const int wdst = (tid >> 6) * 512;

    f32x4 acc[4][4];
#pragma unroll
    for (int m = 0; m < 4; ++m)
#pragma unroll
        for (int n = 0; n < 4; ++n) acc[m][n] = (f32x4){0.f, 0.f, 0.f, 0.f};

#define STAGEWQ(e0_)                                                           \
    {                                                                          \
        _Pragma("unroll")                                                      \
        for (int p = 0; p < 2; ++p) {                                          \
            int h = p * 64 + wh;                                               \
            int ec = wk8 ^ ((h & 3) << 3);                                     \
            size_t g = (size_t)h * EE + (e0_) + ec;                            \
            gload_lds16(&wqh[g], &smB[0][p * 2048 + wdst]);                    \
            gload_lds16(&wql[g], &smB[1][p * 2048 + wdst]);                    \
        }                                                                      \
    }

    auto LOADA = [&](int e0, f32x4 xa[4]) {
#pragma unroll
        for (int p = 0; p < 4; ++p)
            xa[p] = *(const f32x4*)&inp[((size_t)b * TT + t0 + p * 32 + lrow) * EE + e0 + lkq * 4];
    };
    auto STOREA = [&](const f32x4 xa[4]) {
#pragma unroll
        for (int p = 0; p < 4; ++p) {
            int row = p * 32 + lrow;
            s16x4 hi, lo;
#pragma unroll
            for (int c = 0; c < 4; ++c) { short h, l; bfsplit(xa[p][c], h, l); hi[c] = h; lo[c] = l; }
            *(s16x4*)&smA[0][row * LDW + lkq * 4] = hi;
            *(s16x4*)&smA[1][row * LDW + lkq * 4] = lo;
        }
    };

    f32x4 xa[4];
    LOADA(0, xa);
    STOREA(xa);
    STAGEWQ(0);
    __syncthreads();

    for (int step = 0; step < 32; ++step) {
        if (step < 31) LOADA((step + 1) * BK, xa);
        bf16x8 ah[4], al[4];
#pragma unroll
        for (int m = 0; m < 4; ++m) {
            int r = wr * 64 + m * 16 + fr;
            ah[m] = *(const bf16x8*)&smA[0][r * LDW + fq * 8];
            al[m] = *(const bf16x8*)&smA[1][r * LDW + fq * 8];
        }
#pragma unroll
        for (int n = 0; n < 4; ++n) {
            int c = wc * 64 + n * 16 + fr;
            int off = c * 32 + ((fq * 8) ^ ((c & 3) << 3));
            bf16x8 bh = *(const bf16x8*)&smB[0][off];
            bf16x8 bl = *(const bf16x8*)&smB[1][off];
#pragma unroll
            for (int m = 0; m < 4; ++m) {
                acc[m][n] = __builtin_amdgcn_mfma_f32_16x16x32_bf16(ah[m], bh, acc[m][n], 0, 0, 0);
                acc[m][n] = __builtin_amdgcn_mfma_f32_16x16x32_bf16(ah[m], bl, acc[m][n], 0, 0, 0);
                acc[m][n] = __builtin_amdgcn_mfma_f32_16x16x32_bf16(al[m], bh, acc[m][n], 0, 0, 0);
            }
        }
        __syncthreads();
        if (step < 31) {
            STOREA(xa);
            STAGEWQ((step + 1) * BK);
            __syncthreads();
        }
    }
#pragma unroll
    for (int m = 0; m < 4; ++m) {
        int row = t0 + wr * 64 + m * 16 + fq * 4;
#pragma unroll
        for (int n = 0; n < 4; ++n) {
            int col = wc * 64 + n * 16 + fr;
#pragma unroll
            for (int i = 0; i < 4; ++i) {
                short h, l; bfsplit(acc[m][n][i], h, l);
                size_t o = ((size_t)b * TT + row + i) * HH + col;
                qbh[o] = h; qbl[o] = l;
            }
        }
    }
}

// ---------------- shared attn helpers (MUST be identical in k_rowmax / k_attn) ----
__device__ __forceinline__ void stage_k64(const short* __restrict__ srcH, const short* __restrict__ srcL,
                                          size_t rowBase, int tid, short* sh, short* sl)
{
    for (int c = tid; c < 1024; c += 256) {
        int s = c >> 4, h8 = (c & 15) << 3;
        size_t g = (rowBase + s) * HH + h8;
        bf16x8 hv = *(const bf16x8*)&srcH[g];
        bf16x8 lv = *(const bf16x8*)&srcL[g];
        int sw = h8 ^ ((s & 7) << 3);
        *(bf16x8*)&sh[s * 128 + sw] = hv;
        *(bf16x8*)&sl[s * 128 + sw] = lv;
    }
}

__device__ __forceinline__ void load_qfrags(const short* __restrict__ qH, const short* __restrict__ qL,
                                            size_t rowIx, int fq, bf16x8 qh[4], bf16x8 ql[4])
{
    size_t base = rowIx * HH + fq * 8;
#pragma unroll
    for (int k = 0; k < 4; ++k) {
        qh[k] = *(const bf16x8*)&qH[base + k * 32];
        ql[k] = *(const bf16x8*)&qL[base + k * 32];
    }
}

__device__ __forceinline__ void qk_mfma4(const bf16x8 qh[4], const bf16x8 ql[4],
                                         const short* sh, const short* sl,
                                         int fr, int fq, f32x4 acc[4])
{
#pragma unroll
    for (int n = 0; n < 4; ++n) {
        int sc = n * 16 + fr;
        int ro = sc * 128, msk = (sc & 7) << 3;
#pragma unroll
        for (int k = 0; k < 4; ++k) {
            int off = ro + ((k * 32 + fq * 8) ^ msk);
            bf16x8 bh = *(const bf16x8*)&sh[off];
            bf16x8 bl = *(const bf16x8*)&sl[off];
            acc[n] = __builtin_amdgcn_mfma_f32_16x16x32_bf16(ql[k], bh, acc[n], 0, 0, 0);
            acc[n] = __builtin_amdgcn_mfma_f32_16x16x32_bf16(qh[k], bl, acc[n], 0, 0, 0);
            acc[n] = __builtin_amdgcn_mfma_f32_16x16x32_bf16(qh[k], bh, acc[n], 0, 0, 0);
        }
    }
}

// ---------------- K3: rowmax of (qk*scale)^2 via MFMA ----------------
__global__ __launch_bounds__(256) void k_rowmax(
    const short* __restrict__ qbh, const short* __restrict__ qbl,
    const short* __restrict__ kbh, const short* __restrict__ kbl,
    float* __restrict__ rowmax)
{
    __shared__ short Ksh[64 * 128], Ksl[64 * 128];
    const int tid = threadIdx.x, lane = tid & 63, wloc = tid >> 6;
    const int fr = lane & 15, fq = lane >> 4;
    const int split = blockIdx.x, t0 = blockIdx.y * 64, b = blockIdx.z;

    bf16x8 qh[4], ql[4];
    load_qfrags(qbh, qbl, (size_t)b * TT + t0 + wloc * 16 + fr, fq, qh, ql);

    float rm[4] = {0.f, 0.f, 0.f, 0.f};
    const int sBeg = split * SCHUNK;
    for (int st = sBeg; st < sBeg + SCHUNK; st += 64) {
        __syncthreads();
        stage_k64(kbh, kbl, (size_t)b * SS + st, tid, Ksh, Ksl);
        __syncthreads();
        f32x4 acc[4];
#pragma unroll
        for (int n = 0; n < 4; ++n) acc[n] = (f32x4){0.f, 0.f, 0.f, 0.f};
        qk_mfma4(qh, ql, Ksh, Ksl, fr, fq, acc);
#pragma unroll
        for (int n = 0; n < 4; ++n)
#pragma unroll
            for (int i = 0; i < 4; ++i) {
                float w = acc[n][i] * SCALEF;
                rm[i] = fmaxf(rm[i], w * w);
            }
    }
#pragma unroll
    for (int d = 1; d < 16; d <<= 1)
#pragma unroll
        for (int i = 0; i < 4; ++i)
            rm[i] = fmaxf(rm[i], __shfl_xor(rm[i], d, 64));
    if (fr == 0)
#pragma unroll
        for (int i = 0; i < 4; ++i)
            atomicMax((int*)&rowmax[b * TT + t0 + wloc * 16 + fq * 4 + i], __float_as_int(rm[i]));
}

// ---------------- K4: attention (wei, out, colsum-part, qt_loss) via MFMA ----------------
__global__ __launch_bounds__(256) void k_attn(
    const short* __restrict__ qbh, const short* __restrict__ qbl,
    const short* __restrict__ kbh, const short* __restrict__ kbl,
    const short* __restrict__ vTh, const short* __restrict__ vTl,
    const float* __restrict__ rowmax,
    float* __restrict__ outAcc, float* __restrict__ cpart, float* __restrict__ qtloss)
{
    __shared__ short Ksh[64 * 128], Ksl[64 * 128];   // reused as V^T [128][64]
    __shared__ short Ph[64 * 64], Pl[64 * 64];
    __shared__ float csLDS[SCHUNK];
    __shared__ float qred[256];
    const int tid = threadIdx.x, lane = tid & 63, wloc = tid >> 6;
    const int fr = lane & 15, fq = lane >> 4;
    const int split = blockIdx.x, t0 = blockIdx.y * 64, b = blockIdx.z;

    for (int i = tid; i < SCHUNK; i += 256) csLDS[i] = 0.f;

    bf16x8 qh[4], ql[4];
    load_qfrags(qbh, qbl, (size_t)b * TT + t0 + wloc * 16 + fr, fq, qh, ql);

    float inv[4];
#pragma unroll
    for (int i = 0; i < 4; ++i)
        inv[i] = 1.0f / rowmax[b * TT + t0 + wloc * 16 + fq * 4 + i];

    f32x4 oacc[8];
#pragma unroll
    for (int n = 0; n < 8; ++n) oacc[n] = (f32x4){0.f, 0.f, 0.f, 0.f};
    float qtp = 0.f;

    const int sBeg = split * SCHUNK;
    for (int st = sBeg; st < sBeg + SCHUNK; st += 64) {
        __syncthreads();
        stage_k64(kbh, kbl, (size_t)b * SS + st, tid, Ksh, Ksl);
        __syncthreads();
        f32x4 acc[4];
#pragma unroll
        for (int n = 0; n < 4; ++n) acc[n] = (f32x4){0.f, 0.f, 0.f, 0.f};
        qk_mfma4(qh, ql, Ksh, Ksl, fr, fq, acc);

#pragma unroll
        for (int n = 0; n < 4; ++n) {
            float cp = 0.f;
#pragma unroll
            for (int i = 0; i < 4; ++i) {
                float w = acc[n][i] * SCALEF;
                float w2 = w * w;
                float wei = w2 * inv[i];
                qtp += logf(wei + 1e-4f);
                cp += wei;
                short h, l; bfsplit(wei, h, l);
                int r = wloc * 16 + fq * 4 + i;
                int sw = (n * 16 + fr) ^ ((r & 7) << 3);
                Ph[r * 64 + sw] = h;
                Pl[r * 64 + sw] = l;
            }
            cp += __shfl_xor(cp, 16, 64);
            cp += __shfl_xor(cp, 32, 64);
            if (fq == 0) atomicAdd(&csLDS[st - sBeg + n * 16 + fr], cp);
        }
        __syncthreads();
        // stage V^T tile [128 h][64 s]
        for (int c = tid; c < 1024; c += 256) {
            int h = c >> 3, s8 = (c & 7) << 3;
            size_t g = ((size_t)b * HH + h) * SS + st + s8;
            bf16x8 hv = *(const bf16x8*)&vTh[g];
            bf16x8 lv = *(const bf16x8*)&vTl[g];
            int sw = s8 ^ ((h & 7) << 3);
            *(bf16x8*)&Ksh[h * 64 + sw] = hv;
            *(bf16x8*)&Ksl[h * 64 + sw] = lv;
        }
        __syncthreads();
        // PV
        {
            int rA = wloc * 16 + fr;
#pragma unroll
            for (int k = 0; k < 2; ++k) {
                int offA = rA * 64 + ((k * 32 + fq * 8) ^ ((rA & 7) << 3));
                bf16x8 ph = *(const bf16x8*)&Ph[offA];
                bf16x8 pl = *(const bf16x8*)&Pl[offA];
#pragma unroll
                for (int n = 0; n < 8; ++n) {
                    int hc = n * 16 + fr;
                    int offB = hc * 64 + ((k * 32 + fq * 8) ^ ((hc & 7) << 3));
                    bf16x8 vh = *(const bf16x8*)&Ksh[offB];
                    bf16x8 vl = *(const bf16x8*)&Ksl[offB];
                    oacc[n] = __builtin_amdgcn_mfma_f32_16x16x32_bf16(pl, vh, oacc[n], 0, 0, 0);
                    oacc[n] = __builtin_amdgcn_mfma_f32_16x16x32_bf16(ph, vl, oacc[n], 0, 0, 0);
                    oacc[n] = __builtin_amdgcn_mfma_f32_16x16x32_bf16(ph, vh, oacc[n], 0, 0, 0);
                }
            }
        }
    }

#pragma unroll
    for (int n = 0; n < 8; ++n)
#pragma unroll
        for (int i = 0; i < 4; ++i)
            atomicAdd(&outAcc[((size_t)b * TT + t0 + wloc * 16 + fq * 4 + i) * HH + n * 16 + fr],
                      oacc[n][i]);

    qred[tid] = qtp;
    __syncthreads();
    for (int off = 128; off; off >>= 1) {
        if (tid < off) qred[tid] += qred[tid + off];
        __syncthreads();
    }
    if (tid == 0) atomicAdd(qtloss, qred[0]);

    const int tt = blockIdx.y;
    for (int s = tid; s < SCHUNK; s += 256)
        cpart[((size_t)(b * 16 + tt)) * SS + sBeg + s] = csLDS[s];
}

// ---------------- K5: rank + sortable keys (deterministic colsum reduce) ----------------
__global__ __launch_bounds__(256) void k_rank(
    const float* __restrict__ cpart, const float* __restrict__ mrank,
    unsigned long long* __restrict__ keys, float* __restrict__ csum)
{
    const int b = blockIdx.x, tid = threadIdx.x;
    __shared__ float red[256];
    float p = 0.f;
    for (int s = tid; s < SS; s += 256) {
        float cs = 0.f;
#pragma unroll
        for (int tt = 0; tt < 16; ++tt) cs += cpart[((size_t)(b * 16 + tt)) * SS + s];
        csum[b * SS + s] = cs;
        p += cs;
    }
    red[tid] = p;
    __syncthreads();
    for (int off = 128; off; off >>= 1) {
        if (tid < off) red[tid] += red[tid + off];
        __syncthreads();
    }
    float mean = red[0] / (float)SS;
    for (int m = tid; m < MM; m += 256) {
        float rank = ((mrank[b * MM + m] + csum[b * SS + m] / mean) - 1.0f) - 0.01f;
        keys[b * MM + m] = ((unsigned long long)(unsigned)(~f2ord(rank)) << 32) | (unsigned)m;
    }
}

// ---------------- K6: in-LDS bitonic sort ----------------
__global__ __launch_bounds__(1024) void k_sort(unsigned long long* __restrict__ keys)
{
    __shared__ unsigned long long a[MM];
    const int b = blockIdx.x, tid = threadIdx.x;
    for (int i = tid; i < MM; i += 1024) a[i] = keys[(size_t)b * MM + i];
    __syncthreads();
    for (int k = 2; k <= MM; k <<= 1) {
        for (int j = k >> 1; j > 0; j >>= 1) {
            for (int i = tid; i < MM; i += 1024) {
                int l = i ^ j;
                if (l > i) {
                    unsigned long long x = a[i], y = a[l];
                    bool up = ((i & k) == 0);
                    if ((x > y) == up) { a[i] = y; a[l] = x; }
                }
            }
            __syncthreads();
        }
    }
    for (int i = tid; i < MM; i += 1024) keys[(size_t)b * MM + i] = a[i];
}

// ---------------- K7: scatter sorted memory / dist / rank ----------------
__global__ __launch_bounds__(256) void k_scatter(
    const float* __restrict__ memory, const int* __restrict__ mbd,
    const int* __restrict__ bpl, const float* __restrict__ inp,
    const unsigned long long* __restrict__ keys,
    float* __restrict__ nmem, float* __restrict__ ndist, float* __restrict__ nrank)
{
    const int blk = blockIdx.x;
    const int b = blk >> 10;
    const int p0 = (blk & 1023) * 8;
    const bool reset = (bpl[b] == 0);
    const int tid = threadIdx.x;
    const f32x4 zero = (f32x4){0.f, 0.f, 0.f, 0.f};
    for (int r = 0; r < 8; ++r) {
        int p = p0 + r;
        float* drow = &nmem[((size_t)b * MM + p) * EE];
        if (p < RKEEP) {
            unsigned long long key = keys[(size_t)b * MM + p];
            int src = (int)(unsigned)(key & 0xFFFFFFFFu);
            const float* srow = &memory[((size_t)b * MM + src) * EE];
            *(f32x4*)&drow[tid * 4] = reset ? zero : *(const f32x4*)&srow[tid * 4];
            if (tid == 0) {
                ndist[b * MM + p] = reset ? 1.0f : (float)(mbd[b * MM + src] + 1);
                nrank[b * MM + p] = ord2f(~(unsigned)(key >> 32));
            }
        } else {
            int irow = p - RKEEP;
            const float* srow = &inp[((size_t)b * TT + irow) * EE];
            *(f32x4*)&drow[tid * 4] = *(const f32x4*)&srow[tid * 4];
            if (tid == 0) { ndist[b * MM + p] = 0.f; nrank[b * MM + p] = 1.0f; }
        }
    }
}

// ---------------- launcher ----------------
extern "C" void kernel_launch(void* const* d_in, const int* in_sizes, int n_in,
                              void* d_out, int out_size, void* d_ws, size_t ws_size,
                              hipStream_t stream)
{
    const int*   bpl    = (const int*)d_in[0];
    const float* inp    = (const float*)d_in[1];
    const float* memory = (const float*)d_in[2];
    const int*   mbd    = (const int*)d_in[3];
    const float* mrank  = (const float*)d_in[4];
    const float* pos    = (const float*)d_in[5];
    const float* Wk     = (const float*)d_in[6];
    const float* Wq     = (const float*)d_in[7];
    const float* Wv     = (const float*)d_in[8];

    float* out   = (float*)d_out;                    // [B,T,H]
    float* qtl   = out + (size_t)BB * TT * HH;       // scalar
    float* nmem  = qtl + 1;                          // [B,M,E]
    float* ndist = nmem + (size_t)BB * MM * EE;      // [B,M]
    float* nrank = ndist + (size_t)BB * MM;          // [B,M]

    char* w = (char*)d_ws;
    short* qbh = (short*)w; w += (size_t)BB * TT * HH * 2;
    short* qbl = (short*)w; w += (size_t)BB * TT * HH * 2;
    short* kbh = (short*)w; w += (size_t)BB * SS * HH * 2;
    short* kbl = (short*)w; w += (size_t)BB * SS * HH * 2;
    short* vTh = (short*)w; w += (size_t)BB * HH * SS * 2;
    short* vTl = (short*)w; w += (size_t)BB * HH * SS * 2;
    float* rmax = (float*)w; w += (size_t)BB * TT * 4;
    float* csum = (float*)w; w += (size_t)BB * SS * 4;
    float* cpart = (float*)w; w += (size_t)BB * 16 * SS * 4;
    unsigned long long* keys = (unsigned long long*)w; w += (size_t)BB * MM * 8;
    short* wkh = (short*)w; w += (size_t)HH * EE * 2;
    short* wkl = (short*)w; w += (size_t)HH * EE * 2;
    short* wqh = (short*)w; w += (size_t)HH * EE * 2;
    short* wql = (short*)w; w += (size_t)HH * EE * 2;
    short* wvh = (short*)w; w += (size_t)HH * EE * 2;
    short* wvl = (short*)w; w += (size_t)HH * EE * 2;
    if ((size_t)(w - (char*)d_ws) > ws_size) return;

    hipMemsetAsync(d_out, 0, ((size_t)BB * TT * HH + 1) * 4, stream);
    hipMemsetAsync(rmax, 0, (size_t)BB * TT * 4, stream);

    k_wsplit <<<384, 256, 0, stream>>>(Wk, Wq, Wv, wkh, wkl, wqh, wql, wvh, wvl);
    k_proj_kv<<<dim3(SS / 128, BB), 256, 0, stream>>>(memory, mbd, bpl, pos, inp,
                                                      wkh, wkl, wvh, wvl,
                                                      kbh, kbl, vTh, vTl);
    k_proj_q <<<dim3(TT / 128, BB), 256, 0, stream>>>(inp, wqh, wql, qbh, qbl);
    k_rowmax <<<dim3(NSPLIT, TT / 64, BB), 256, 0, stream>>>(qbh, qbl, kbh, kbl, rmax);
    k_attn   <<<dim3(NSPLIT, TT / 64, BB), 256, 0, stream>>>(qbh, qbl, kbh, kbl, vTh, vTl,
                                                             rmax, out, cpart, qtl);
    k_rank   <<<BB, 256, 0, stream>>>(cpart, mrank, keys, csum);
    k_sort   <<<BB, 1024, 0, stream>>>(keys);
    k_scatter<<<BB * (MM / 8), 256, 0, stream>>>(memory, mbd, bpl, inp, keys, nmem, ndist, nrank);
}

// Round 5
// 818.097 us; speedup vs baseline: 4.4360x; 1.1619x over previous
//
#include <hip/hip_runtime.h>
#include <hip/hip_bf16.h>
#include <stdint.h>

#define BB 8
#define TT 1024
#define MM 8192
#define EE 1024
#define HH 128
#define SS (MM + TT)          // 9216
#define RKEEP (MM - 1024)     // 7168 rows kept after eviction
#define NSPLIT 8
#define SCHUNK (SS / NSPLIT)  // 1152
#define BK 32
#define LDW 40                // A-tile LDS row stride in shorts (80B, conflict-benign)

typedef __attribute__((ext_vector_type(8))) short bf16x8;
typedef __attribute__((ext_vector_type(4))) short s16x4;
typedef __attribute__((ext_vector_type(4))) float f32x4;

static __device__ __forceinline__ unsigned f2ord(float f) {
    unsigned u = __float_as_uint(f);
    return u ^ ((u & 0x80000000u) ? 0xFFFFFFFFu : 0x80000000u);
}
static __device__ __forceinline__ float ord2f(unsigned o) {
    unsigned u = (o & 0x80000000u) ? (o ^ 0x80000000u) : ~o;
    return __uint_as_float(u);
}
static __device__ __forceinline__ unsigned short f2bf(float x) {
    unsigned u = __float_as_uint(x);
    unsigned r = u + 0x7FFFu + ((u >> 16) & 1u);   // RNE
    return (unsigned short)(r >> 16);
}
static __device__ __forceinline__ float bf2f(unsigned short h) {
    return __uint_as_float(((unsigned)h) << 16);
}
static __device__ __forceinline__ void bfsplit(float x, short& hi, short& lo) {
    unsigned short h = f2bf(x);
    hi = (short)h;
    lo = (short)f2bf(x - bf2f(h));
}

// async global->LDS, 16B per lane; dest = wave-uniform base + lane*16
static __device__ __forceinline__ void gload_lds16(const short* g, short* l) {
    __builtin_amdgcn_global_load_lds(
        (const __attribute__((address_space(1))) void*)g,
        (__attribute__((address_space(3))) void*)l, 16, 0, 0);
}

__device__ const float SCALEF = (float)(1.0 / 96.0);  // (M+T)^-0.5

// ---------------- K0: pre-split weights (K,Q: hi+lo; V: hi only) ----------------
__global__ __launch_bounds__(256) void k_wsplit(
    const float* __restrict__ Wk, const float* __restrict__ Wq, const float* __restrict__ Wv,
    short* __restrict__ wkh, short* __restrict__ wkl,
    short* __restrict__ wqh, short* __restrict__ wql,
    short* __restrict__ wvh)
{
    int idx = blockIdx.x * 256 + threadIdx.x;     // 3 * 32768 threads, 4 elems each
    int m = idx >> 15;
    int o4 = (idx & 32767) * 4;
    const float* W = m == 0 ? Wk : (m == 1 ? Wq : Wv);
    f32x4 v = *(const f32x4*)&W[o4];
    s16x4 hi, lo;
#pragma unroll
    for (int j = 0; j < 4; ++j) { short h, l; bfsplit(v[j], h, l); hi[j] = h; lo[j] = l; }
    if (m == 0) { *(s16x4*)&wkh[o4] = hi; *(s16x4*)&wkl[o4] = lo; }
    else if (m == 1) { *(s16x4*)&wqh[o4] = hi; *(s16x4*)&wql[o4] = lo; }
    else { *(s16x4*)&wvh[o4] = hi; }
}

// ---------------- K1: fused K,V projection ----------------
__global__ __launch_bounds__(256, 2) void k_proj_kv(
    const float* __restrict__ memory, const int* __restrict__ mbd,
    const int* __restrict__ bpl, const float* __restrict__ pos_table,
    const float* __restrict__ inp,
    const short* __restrict__ wkh, const short* __restrict__ wkl,
    const short* __restrict__ wvh,
    short* __restrict__ kbh, short* __restrict__ kbl,
    short* __restrict__ vTh)
{
    __shared__ __align__(16) short smA[2][128 * LDW];      // Ah, Al (20KB)
    __shared__ __align__(16) short smB[2][3][128 * 32];    // dbuf x {kh,kl,vh} (48KB)

    const int tid = threadIdx.x;
    const int b   = blockIdx.y;
    const int s0  = blockIdx.x * 128;
    const bool reset = (bpl[b] == 0);
    const int lane = tid & 63, wid = tid >> 6;
    const int wr = wid >> 1, wc = wid & 1;
    const int fr = lane & 15, fq = lane >> 4;
    const int lrow = tid >> 3, lkq = tid & 7;

    int pixr[4];
    const float* aptr[4];
#pragma unroll
    for (int p = 0; p < 4; ++p) {
        int s = s0 + p * 32 + lrow;
        if (s < MM) {
            int d = reset ? 1 : (mbd[b * MM + s] + 1);
            pixr[p] = 31 - __clz(d);
            aptr[p] = reset ? nullptr : &memory[((size_t)b * MM + s) * EE];
        } else {
            pixr[p] = -1;
            aptr[p] = &inp[((size_t)b * TT + (s - MM)) * EE];
        }
    }

    f32x4 accK[4][4], accV[4][4];
#pragma unroll
    for (int m = 0; m < 4; ++m)
#pragma unroll
        for (int n = 0; n < 4; ++n) {
            accK[m][n] = (f32x4){0.f, 0.f, 0.f, 0.f};
            accV[m][n] = (f32x4){0.f, 0.f, 0.f, 0.f};
        }

    const int wh   = (tid >> 2);
    const int wk8  = (tid & 3) * 8;
    const int wdst = (tid >> 6) * 512;

    auto STAGEW = [&](int e0, int buf) {
#pragma unroll
        for (int p = 0; p < 2; ++p) {
            int h = p * 64 + wh;
            int ec = wk8 ^ ((h & 3) << 3);
            size_t g = (size_t)h * EE + e0 + ec;
            gload_lds16(&wkh[g], &smB[buf][0][p * 2048 + wdst]);
            gload_lds16(&wkl[g], &smB[buf][1][p * 2048 + wdst]);
            gload_lds16(&wvh[g], &smB[buf][2][p * 2048 + wdst]);
        }
    };
    auto LOADA = [&](int e0, f32x4 xa[4]) {
#pragma unroll
        for (int p = 0; p < 4; ++p) {
            f32x4 v = (f32x4){0.f, 0.f, 0.f, 0.f};
            if (aptr[p]) v = *(const f32x4*)&aptr[p][e0 + lkq * 4];
            if (pixr[p] >= 0) {
                f32x4 pt = *(const f32x4*)&pos_table[(size_t)pixr[p] * EE + e0 + lkq * 4];
                v[0] += pt[0]; v[1] += pt[1]; v[2] += pt[2]; v[3] += pt[3];
            }
            xa[p] = v;
        }
    };
    auto STOREA = [&](const f32x4 xa[4]) {
#pragma unroll
        for (int p = 0; p < 4; ++p) {
            int row = p * 32 + lrow;
            s16x4 hi, lo;
#pragma unroll
            for (int c = 0; c < 4; ++c) { short h, l; bfsplit(xa[p][c], h, l); hi[c] = h; lo[c] = l; }
            *(s16x4*)&smA[0][row * LDW + lkq * 4] = hi;
            *(s16x4*)&smA[1][row * LDW + lkq * 4] = lo;
        }
    };

    f32x4 xa[4];
    LOADA(0, xa);
    STOREA(xa);
    STAGEW(0, 0);
    __syncthreads();

    for (int step = 0; step < 32; ++step) {
        const int buf = step & 1;
        if (step < 31) {
            LOADA((step + 1) * BK, xa);       // reg prefetch of next A tile
            STAGEW((step + 1) * BK, buf ^ 1); // async W loads land during MFMA phase
        }

        bf16x8 ah[4], al[4];
#pragma unroll
        for (int m = 0; m < 4; ++m) {
            int r = wr * 64 + m * 16 + fr;
            ah[m] = *(const bf16x8*)&smA[0][r * LDW + fq * 8];
            al[m] = *(const bf16x8*)&smA[1][r * LDW + fq * 8];
        }
#pragma unroll
        for (int n = 0; n < 4; ++n) {
            int c = wc * 64 + n * 16 + fr;
            int off = c * 32 + ((fq * 8) ^ ((c & 3) << 3));
            bf16x8 kh = *(const bf16x8*)&smB[buf][0][off];
            bf16x8 kl = *(const bf16x8*)&smB[buf][1][off];
            bf16x8 vh = *(const bf16x8*)&smB[buf][2][off];
#pragma unroll
            for (int m = 0; m < 4; ++m) {
                accK[m][n] = __builtin_amdgcn_mfma_f32_16x16x32_bf16(ah[m], kh, accK[m][n], 0, 0, 0);
                accK[m][n] = __builtin_amdgcn_mfma_f32_16x16x32_bf16(ah[m], kl, accK[m][n], 0, 0, 0);
                accK[m][n] = __builtin_amdgcn_mfma_f32_16x16x32_bf16(al[m], kh, accK[m][n], 0, 0, 0);
                accV[m][n] = __builtin_amdgcn_mfma_f32_16x16x32_bf16(ah[m], vh, accV[m][n], 0, 0, 0);
                accV[m][n] = __builtin_amdgcn_mfma_f32_16x16x32_bf16(al[m], vh, accV[m][n], 0, 0, 0);
            }
        }
        if (step < 31) {
            __syncthreads();     // MFMA reads done everywhere; STAGEW drained
            STOREA(xa);          // write next A tile
            __syncthreads();     // lgkm-only drain, cheap
        }
    }

    // ---- K epilogue ----
#pragma unroll
    for (int m = 0; m < 4; ++m) {
        int row = s0 + wr * 64 + m * 16 + fq * 4;
#pragma unroll
        for (int n = 0; n < 4; ++n) {
            int col = wc * 64 + n * 16 + fr;
#pragma unroll
            for (int i = 0; i < 4; ++i) {
                short h, l; bfsplit(accK[m][n][i], h, l);
                size_t o = ((size_t)b * SS + row + i) * HH + col;
                kbh[o] = h; kbl[o] = l;
            }
        }
    }
    // ---- V epilogue: transpose via LDS (aliasing smB), write [b][h][s] hi plane ----
    float* tpT = (float*)smB;   // [32][132] f32 = 16.9KB
#pragma unroll
    for (int p = 0; p < 2; ++p)
#pragma unroll
        for (int half = 0; half < 2; ++half) {
            __syncthreads();
            if (wc == p) {
#pragma unroll
                for (int m = 0; m < 4; ++m)
#pragma unroll
                    for (int n2 = 0; n2 < 2; ++n2) {
                        int n = half * 2 + n2;
                        int cl = n2 * 16 + fr;
                        int row = wr * 64 + m * 16 + fq * 4;
                        *(f32x4*)&tpT[cl * 132 + row] = accV[m][n];
                    }
            }
            __syncthreads();
            for (int idx = tid; idx < 32 * 32; idx += 256) {
                int hcl = idx >> 5, s4 = (idx & 31) << 2;
                f32x4 v = *(const f32x4*)&tpT[hcl * 132 + s4];
                s16x4 hi;
#pragma unroll
                for (int j = 0; j < 4; ++j) hi[j] = (short)f2bf(v[j]);
                size_t o = ((size_t)b * HH + p * 64 + half * 32 + hcl) * SS + s0 + s4;
                *(s16x4*)&vTh[o] = hi;
            }
        }
}

// ---------------- K2: Q projection ----------------
__global__ __launch_bounds__(256, 2) void k_proj_q(
    const float* __restrict__ inp,
    const short* __restrict__ wqh, const short* __restrict__ wql,
    short* __restrict__ qbh, short* __restrict__ qbl)
{
    __shared__ __align__(16) short smA[2][128 * LDW];
    __shared__ __align__(16) short smB[2][2][128 * 32];
    const int tid = threadIdx.x;
    const int b   = blockIdx.y;
    const int t0  = blockIdx.x * 128;
    const int lane = tid & 63, wid = tid >> 6;
    const int wr = wid >> 1, wc = wid & 1;
    const int fr = lane & 15, fq = lane >> 4;
    const int lrow = tid >> 3, lkq = tid & 7;
    const int wh   = (tid >> 2);
    const int wk8  = (tid & 3) * 8;
    const int wdst = (tid >> 6) * 512;

    f32x4 acc[4][4];
#pragma unroll
    for (int m = 0; m < 4; ++m)
#pragma unroll
        for (int n = 0; n < 4; ++n) acc[m][n] = (f32x4){0.f, 0.f, 0.f, 0.f};

    auto STAGEWQ = [&](int e0, int buf) {
#pragma unroll
        for (int p = 0; p < 2; ++p) {
            int h = p * 64 + wh;
            int ec = wk8 ^ ((h & 3) << 3);
            size_t g = (size_t)h * EE + e0 + ec;
            gload_lds16(&wqh[g], &smB[buf][0][p * 2048 + wdst]);
            gload_lds16(&wql[g], &smB[buf][1][p * 2048 + wdst]);
        }
    };
    auto LOADA = [&](int e0, f32x4 xa[4]) {
#pragma unroll
        for (int p = 0; p < 4; ++p)
            xa[p] = *(const f32x4*)&inp[((size_t)b * TT + t0 + p * 32 + lrow) * EE + e0 + lkq * 4];
    };
    auto STOREA = [&](const f32x4 xa[4]) {
#pragma unroll
        for (int p = 0; p < 4; ++p) {
            int row = p * 32 + lrow;
            s16x4 hi, lo;
#pragma unroll
            for (int c = 0; c < 4; ++c) { short h, l; bfsplit(xa[p][c], h, l); hi[c] = h; lo[c] = l; }
            *(s16x4*)&smA[0][row * LDW + lkq * 4] = hi;
            *(s16x4*)&smA[1][row * LDW + lkq * 4] = lo;
        }
    };

    f32x4 xa[4];
    LOADA(0, xa);
    STOREA(xa);
    STAGEWQ(0, 0);
    __syncthreads();

    for (int step = 0; step < 32; ++step) {
        const int buf = step & 1;
        if (step < 31) {
            LOADA((step + 1) * BK, xa);
            STAGEWQ((step + 1) * BK, buf ^ 1);
        }
        bf16x8 ah[4], al[4];
#pragma unroll
        for (int m = 0; m < 4; ++m) {
            int r = wr * 64 + m * 16 + fr;
            ah[m] = *(const bf16x8*)&smA[0][r * LDW + fq * 8];
            al[m] = *(const bf16x8*)&smA[1][r * LDW + fq * 8];
        }
#pragma unroll
        for (int n = 0; n < 4; ++n) {
            int c = wc * 64 + n * 16 + fr;
            int off = c * 32 + ((fq * 8) ^ ((c & 3) << 3));
            bf16x8 bh = *(const bf16x8*)&smB[buf][0][off];
            bf16x8 bl = *(const bf16x8*)&smB[buf][1][off];
#pragma unroll
            for (int m = 0; m < 4; ++m) {
                acc[m][n] = __builtin_amdgcn_mfma_f32_16x16x32_bf16(ah[m], bh, acc[m][n], 0, 0, 0);
                acc[m][n] = __builtin_amdgcn_mfma_f32_16x16x32_bf16(ah[m], bl, acc[m][n], 0, 0, 0);
                acc[m][n] = __builtin_amdgcn_mfma_f32_16x16x32_bf16(al[m], bh, acc[m][n], 0, 0, 0);
            }
        }
        if (step < 31) {
            __syncthreads();
            STOREA(xa);
            __syncthreads();
        }
    }
#pragma unroll
    for (int m = 0; m < 4; ++m) {
        int row = t0 + wr * 64 + m * 16 + fq * 4;
#pragma unroll
        for (int n = 0; n < 4; ++n) {
            int col = wc * 64 + n * 16 + fr;
#pragma unroll
            for (int i = 0; i < 4; ++i) {
                short h, l; bfsplit(acc[m][n][i], h, l);
                size_t o = ((size_t)b * TT + row + i) * HH + col;
                qbh[o] = h; qbl[o] = l;
            }
        }
    }
}

// ---------------- shared attn helpers (MUST be identical in k_rowmax / k_attn) ----
__device__ __forceinline__ void stage_k64(const short* __restrict__ srcH, const short* __restrict__ srcL,
                                          size_t rowBase, int tid, short* sh, short* sl)
{
    for (int c = tid; c < 1024; c += 256) {
        int s = c >> 4, h8 = (c & 15) << 3;
        size_t g = (rowBase + s) * HH + h8;
        bf16x8 hv = *(const bf16x8*)&srcH[g];
        bf16x8 lv = *(const bf16x8*)&srcL[g];
        int sw = h8 ^ ((s & 7) << 3);
        *(bf16x8*)&sh[s * 128 + sw] = hv;
        *(bf16x8*)&sl[s * 128 + sw] = lv;
    }
}

__device__ __forceinline__ void load_qfrags(const short* __restrict__ qH, const short* __restrict__ qL,
                                            size_t rowIx, int fq, bf16x8 qh[4], bf16x8 ql[4])
{
    size_t base = rowIx * HH + fq * 8;
#pragma unroll
    for (int k = 0; k < 4; ++k) {
        qh[k] = *(const bf16x8*)&qH[base + k * 32];
        ql[k] = *(const bf16x8*)&qL[base + k * 32];
    }
}

__device__ __forceinline__ void qk_mfma4(const bf16x8 qh[4], const bf16x8 ql[4],
                                         const short* sh, const short* sl,
                                         int fr, int fq, f32x4 acc[4])
{
#pragma unroll
    for (int n = 0; n < 4; ++n) {
        int sc = n * 16 + fr;
        int ro = sc * 128, msk = (sc & 7) << 3;
#pragma unroll
        for (int k = 0; k < 4; ++k) {
            int off = ro + ((k * 32 + fq * 8) ^ msk);
            bf16x8 bh = *(const bf16x8*)&sh[off];
            bf16x8 bl = *(const bf16x8*)&sl[off];
            acc[n] = __builtin_amdgcn_mfma_f32_16x16x32_bf16(ql[k], bh, acc[n], 0, 0, 0);
            acc[n] = __builtin_amdgcn_mfma_f32_16x16x32_bf16(qh[k], bl, acc[n], 0, 0, 0);
            acc[n] = __builtin_amdgcn_mfma_f32_16x16x32_bf16(qh[k], bh, acc[n], 0, 0, 0);
        }
    }
}

// ---------------- K3: rowmax of (qk*scale)^2 via MFMA ----------------
__global__ __launch_bounds__(256) void k_rowmax(
    const short* __restrict__ qbh, const short* __restrict__ qbl,
    const short* __restrict__ kbh, const short* __restrict__ kbl,
    float* __restrict__ rowmax)
{
    __shared__ short Ksh[64 * 128], Ksl[64 * 128];
    const int tid = threadIdx.x, lane = tid & 63, wloc = tid >> 6;
    const int fr = lane & 15, fq = lane >> 4;
    const int split = blockIdx.x, t0 = blockIdx.y * 64, b = blockIdx.z;

    bf16x8 qh[4], ql[4];
    load_qfrags(qbh, qbl, (size_t)b * TT + t0 + wloc * 16 + fr, fq, qh, ql);

    float rm[4] = {0.f, 0.f, 0.f, 0.f};
    const int sBeg = split * SCHUNK;
    for (int st = sBeg; st < sBeg + SCHUNK; st += 64) {
        __syncthreads();
        stage_k64(kbh, kbl, (size_t)b * SS + st, tid, Ksh, Ksl);
        __syncthreads();
        f32x4 acc[4];
#pragma unroll
        for (int n = 0; n < 4; ++n) acc[n] = (f32x4){0.f, 0.f, 0.f, 0.f};
        qk_mfma4(qh, ql, Ksh, Ksl, fr, fq, acc);
#pragma unroll
        for (int n = 0; n < 4; ++n)
#pragma unroll
            for (int i = 0; i < 4; ++i) {
                float w = acc[n][i] * SCALEF;
                rm[i] = fmaxf(rm[i], w * w);
            }
    }
#pragma unroll
    for (int d = 1; d < 16; d <<= 1)
#pragma unroll
        for (int i = 0; i < 4; ++i)
            rm[i] = fmaxf(rm[i], __shfl_xor(rm[i], d, 64));
    if (fr == 0)
#pragma unroll
        for (int i = 0; i < 4; ++i)
            atomicMax((int*)&rowmax[b * TT + t0 + wloc * 16 + fq * 4 + i], __float_as_int(rm[i]));
}

// ---------------- K4: attention (wei, out, colsum-part, qt_loss) via MFMA ----------------
__global__ __launch_bounds__(256) void k_attn(
    const short* __restrict__ qbh, const short* __restrict__ qbl,
    const short* __restrict__ kbh, const short* __restrict__ kbl,
    const short* __restrict__ vTh,
    const float* __restrict__ rowmax,
    float* __restrict__ outAcc, float* __restrict__ cpart, float* __restrict__ qtloss)
{
    __shared__ short Ksh[64 * 128], Ksl[64 * 128];   // Ksh reused as V^T [128][64]
    __shared__ short Ph[64 * 64], Pl[64 * 64];
    __shared__ float csLDS[SCHUNK];
    __shared__ float qred[256];
    const int tid = threadIdx.x, lane = tid & 63, wloc = tid >> 6;
    const int fr = lane & 15, fq = lane >> 4;
    const int split = blockIdx.x, t0 = blockIdx.y * 64, b = blockIdx.z;

    for (int i = tid; i < SCHUNK; i += 256) csLDS[i] = 0.f;

    bf16x8 qh[4], ql[4];
    load_qfrags(qbh, qbl, (size_t)b * TT + t0 + wloc * 16 + fr, fq, qh, ql);

    float inv[4];
#pragma unroll
    for (int i = 0; i < 4; ++i)
        inv[i] = 1.0f / rowmax[b * TT + t0 + wloc * 16 + fq * 4 + i];

    f32x4 oacc[8];
#pragma unroll
    for (int n = 0; n < 8; ++n) oacc[n] = (f32x4){0.f, 0.f, 0.f, 0.f};
    float qtp = 0.f;

    const int sBeg = split * SCHUNK;
    for (int st = sBeg; st < sBeg + SCHUNK; st += 64) {
        __syncthreads();
        stage_k64(kbh, kbl, (size_t)b * SS + st, tid, Ksh, Ksl);
        __syncthreads();
        f32x4 acc[4];
#pragma unroll
        for (int n = 0; n < 4; ++n) acc[n] = (f32x4){0.f, 0.f, 0.f, 0.f};
        qk_mfma4(qh, ql, Ksh, Ksl, fr, fq, acc);

#pragma unroll
        for (int n = 0; n < 4; ++n) {
            float cp = 0.f;
#pragma unroll
            for (int i = 0; i < 4; ++i) {
                float w = acc[n][i] * SCALEF;
                float w2 = w * w;
                float wei = w2 * inv[i];
                qtp += logf(wei + 1e-4f);
                cp += wei;
                short h, l; bfsplit(wei, h, l);
                int r = wloc * 16 + fq * 4 + i;
                int sw = (n * 16 + fr) ^ ((r & 7) << 3);
                Ph[r * 64 + sw] = h;
                Pl[r * 64 + sw] = l;
            }
            cp += __shfl_xor(cp, 16, 64);
            cp += __shfl_xor(cp, 32, 64);
            if (fq == 0) atomicAdd(&csLDS[st - sBeg + n * 16 + fr], cp);
        }
        __syncthreads();
        // stage V^T tile [128 h][64 s] (hi plane only)
        for (int c = tid; c < 1024; c += 256) {
            int h = c >> 3, s8 = (c & 7) << 3;
            size_t g = ((size_t)b * HH + h) * SS + st + s8;
            bf16x8 hv = *(const bf16x8*)&vTh[g];
            int sw = s8 ^ ((h & 7) << 3);
            *(bf16x8*)&Ksh[h * 64 + sw] = hv;
        }
        __syncthreads();
        // PV
        {
            int rA = wloc * 16 + fr;
#pragma unroll
            for (int k = 0; k < 2; ++k) {
                int offA = rA * 64 + ((k * 32 + fq * 8) ^ ((rA & 7) << 3));
                bf16x8 ph = *(const bf16x8*)&Ph[offA];
                bf16x8 pl = *(const bf16x8*)&Pl[offA];
#pragma unroll
                for (int n = 0; n < 8; ++n) {
                    int hc = n * 16 + fr;
                    int offB = hc * 64 + ((k * 32 + fq * 8) ^ ((hc & 7) << 3));
                    bf16x8 vh = *(const bf16x8*)&Ksh[offB];
                    oacc[n] = __builtin_amdgcn_mfma_f32_16x16x32_bf16(pl, vh, oacc[n], 0, 0, 0);
                    oacc[n] = __builtin_amdgcn_mfma_f32_16x16x32_bf16(ph, vh, oacc[n], 0, 0, 0);
                }
            }
        }
    }

#pragma unroll
    for (int n = 0; n < 8; ++n)
#pragma unroll
        for (int i = 0; i < 4; ++i)
            atomicAdd(&outAcc[((size_t)b * TT + t0 + wloc * 16 + fq * 4 + i) * HH + n * 16 + fr],
                      oacc[n][i]);

    qred[tid] = qtp;
    __syncthreads();
    for (int off = 128; off; off >>= 1) {
        if (tid < off) qred[tid] += qred[tid + off];
        __syncthreads();
    }
    if (tid == 0) atomicAdd(qtloss, qred[0]);

    const int tt = blockIdx.y;
    for (int s = tid; s < SCHUNK; s += 256)
        cpart[((size_t)(b * 16 + tt)) * SS + sBeg + s] = csLDS[s];
}

// ---------------- K5: rank + sortable keys (deterministic colsum reduce) ----------------
__global__ __launch_bounds__(256) void k_rank(
    const float* __restrict__ cpart, const float* __restrict__ mrank,
    unsigned long long* __restrict__ keys, float* __restrict__ csum)
{
    const int b = blockIdx.x, tid = threadIdx.x;
    __shared__ float red[256];
    float p = 0.f;
    for (int s = tid; s < SS; s += 256) {
        float cs = 0.f;
#pragma unroll
        for (int tt = 0; tt < 16; ++tt) cs += cpart[((size_t)(b * 16 + tt)) * SS + s];
        csum[b * SS + s] = cs;
        p += cs;
    }
    red[tid] = p;
    __syncthreads();
    for (int off = 128; off; off >>= 1) {
        if (tid < off) red[tid] += red[tid + off];
        __syncthreads();
    }
    float mean = red[0] / (float)SS;
    for (int m = tid; m < MM; m += 256) {
        float rank = ((mrank[b * MM + m] + csum[b * SS + m] / mean) - 1.0f) - 0.01f;
        keys[b * MM + m] = ((unsigned long long)(unsigned)(~f2ord(rank)) << 32) | (unsigned)m;
    }
}

// ---------------- K6: in-LDS bitonic sort ----------------
__global__ __launch_bounds__(1024) void k_sort(unsigned long long* __restrict__ keys)
{
    __shared__ unsigned long long a[MM];
    const int b = blockIdx.x, tid = threadIdx.x;
    for (int i = tid; i < MM; i += 1024) a[i] = keys[(size_t)b * MM + i];
    __syncthreads();
    for (int k = 2; k <= MM; k <<= 1) {
        for (int j = k >> 1; j > 0; j >>= 1) {
            for (int i = tid; i < MM; i += 1024) {
                int l = i ^ j;
                if (l > i) {
                    unsigned long long x = a[i], y = a[l];
                    bool up = ((i & k) == 0);
                    if ((x > y) == up) { a[i] = y; a[l] = x; }
                }
            }
            __syncthreads();
        }
    }
    for (int i = tid; i < MM; i += 1024) keys[(size_t)b * MM + i] = a[i];
}

// ---------------- K7: scatter sorted memory / dist / rank ----------------
__global__ __launch_bounds__(256) void k_scatter(
    const float* __restrict__ memory, const int* __restrict__ mbd,
    const int* __restrict__ bpl, const float* __restrict__ inp,
    const unsigned long long* __restrict__ keys,
    float* __restrict__ nmem, float* __restrict__ ndist, float* __restrict__ nrank)
{
    const int blk = blockIdx.x;
    const int b = blk >> 10;
    const int p0 = (blk & 1023) * 8;
    const bool reset = (bpl[b] == 0);
    const int tid = threadIdx.x;
    const f32x4 zero = (f32x4){0.f, 0.f, 0.f, 0.f};
    for (int r = 0; r < 8; ++r) {
        int p = p0 + r;
        float* drow = &nmem[((size_t)b * MM + p) * EE];
        if (p < RKEEP) {
            unsigned long long key = keys[(size_t)b * MM + p];
            int src = (int)(unsigned)(key & 0xFFFFFFFFu);
            const float* srow = &memory[((size_t)b * MM + src) * EE];
            *(f32x4*)&drow[tid * 4] = reset ? zero : *(const f32x4*)&srow[tid * 4];
            if (tid == 0) {
                ndist[b * MM + p] = reset ? 1.0f : (float)(mbd[b * MM + src] + 1);
                nrank[b * MM + p] = ord2f(~(unsigned)(key >> 32));
            }
        } else {
            int irow = p - RKEEP;
            const float* srow = &inp[((size_t)b * TT + irow) * EE];
            *(f32x4*)&drow[tid * 4] = *(const f32x4*)&srow[tid * 4];
            if (tid == 0) { ndist[b * MM + p] = 0.f; nrank[b * MM + p] = 1.0f; }
        }
    }
}

// ---------------- launcher ----------------
extern "C" void kernel_launch(void* const* d_in, const int* in_sizes, int n_in,
                              void* d_out, int out_size, void* d_ws, size_t ws_size,
                              hipStream_t stream)
{
    const int*   bpl    = (const int*)d_in[0];
    const float* inp    = (const float*)d_in[1];
    const float* memory = (const float*)d_in[2];
    const int*   mbd    = (const int*)d_in[3];
    const float* mrank  = (const float*)d_in[4];
    const float* pos    = (const float*)d_in[5];
    const float* Wk     = (const float*)d_in[6];
    const float* Wq     = (const float*)d_in[7];
    const float* Wv     = (const float*)d_in[8];

    float* out   = (float*)d_out;                    // [B,T,H]
    float* qtl   = out + (size_t)BB * TT * HH;       // scalar
    float* nmem  = qtl + 1;                          // [B,M,E]
    float* ndist = nmem + (size_t)BB * MM * EE;      // [B,M]
    float* nrank = ndist + (size_t)BB * MM;          // [B,M]

    char* w = (char*)d_ws;
    short* qbh = (short*)w; w += (size_t)BB * TT * HH * 2;
    short* qbl = (short*)w; w += (size_t)BB * TT * HH * 2;
    short* kbh = (short*)w; w += (size_t)BB * SS * HH * 2;
    short* kbl = (short*)w; w += (size_t)BB * SS * HH * 2;
    short* vTh = (short*)w; w += (size_t)BB * HH * SS * 2;
    float* rmax = (float*)w; w += (size_t)BB * TT * 4;
    float* csum = (float*)w; w += (size_t)BB * SS * 4;
    float* cpart = (float*)w; w += (size_t)BB * 16 * SS * 4;
    unsigned long long* keys = (unsigned long long*)w; w += (size_t)BB * MM * 8;
    short* wkh = (short*)w; w += (size_t)HH * EE * 2;
    short* wkl = (short*)w; w += (size_t)HH * EE * 2;
    short* wqh = (short*)w; w += (size_t)HH * EE * 2;
    short* wql = (short*)w; w += (size_t)HH * EE * 2;
    short* wvh = (short*)w; w += (size_t)HH * EE * 2;
    if ((size_t)(w - (char*)d_ws) > ws_size) return;

    hipMemsetAsync(d_out, 0, ((size_t)BB * TT * HH + 1) * 4, stream);
    hipMemsetAsync(rmax, 0, (size_t)BB * TT * 4, stream);

    k_wsplit <<<384, 256, 0, stream>>>(Wk, Wq, Wv, wkh, wkl, wqh, wql, wvh);
    k_proj_kv<<<dim3(SS / 128, BB), 256, 0, stream>>>(memory, mbd, bpl, pos, inp,
                                                      wkh, wkl, wvh,
                                                      kbh, kbl, vTh);
    k_proj_q <<<dim3(TT / 128, BB), 256, 0, stream>>>(inp, wqh, wql, qbh, qbl);
    k_rowmax <<<dim3(NSPLIT, TT / 64, BB), 256, 0, stream>>>(qbh, qbl, kbh, kbl, rmax);
    k_attn   <<<dim3(NSPLIT, TT / 64, BB), 256, 0, stream>>>(qbh, qbl, kbh, kbl, vTh,
                                                             rmax, out, cpart, qtl);
    k_rank   <<<BB, 256, 0, stream>>>(cpart, mrank, keys, csum);
    k_sort   <<<BB, 1024, 0, stream>>>(keys);
    k_scatter<<<BB * (MM / 8), 256, 0, stream>>>(memory, mbd, bpl, inp, keys, nmem, ndist, nrank);
}

// Round 6
// 735.232 us; speedup vs baseline: 4.9360x; 1.1127x over previous
//
#include <hip/hip_runtime.h>
#include <hip/hip_bf16.h>
#include <stdint.h>

#define BB 8
#define TT 1024
#define MM 8192
#define EE 1024
#define HH 128
#define SS (MM + TT)          // 9216
#define RKEEP (MM - 1024)     // 7168 rows kept after eviction
#define NSPLIT 8
#define SCHUNK (SS / NSPLIT)  // 1152
#define BK 32
#define LDW 40                // A-tile LDS row stride in shorts (80B, conflict-benign)

typedef __attribute__((ext_vector_type(8))) short bf16x8;
typedef __attribute__((ext_vector_type(4))) short s16x4;
typedef __attribute__((ext_vector_type(4))) float f32x4;

static __device__ __forceinline__ unsigned f2ord(float f) {
    unsigned u = __float_as_uint(f);
    return u ^ ((u & 0x80000000u) ? 0xFFFFFFFFu : 0x80000000u);
}
static __device__ __forceinline__ float ord2f(unsigned o) {
    unsigned u = (o & 0x80000000u) ? (o ^ 0x80000000u) : ~o;
    return __uint_as_float(u);
}
static __device__ __forceinline__ unsigned short f2bf(float x) {
    unsigned u = __float_as_uint(x);
    unsigned r = u + 0x7FFFu + ((u >> 16) & 1u);   // RNE
    return (unsigned short)(r >> 16);
}
static __device__ __forceinline__ float bf2f(unsigned short h) {
    return __uint_as_float(((unsigned)h) << 16);
}
static __device__ __forceinline__ void bfsplit(float x, short& hi, short& lo) {
    unsigned short h = f2bf(x);
    hi = (short)h;
    lo = (short)f2bf(x - bf2f(h));
}

// async global->LDS, 16B per lane; dest = wave-uniform base + lane*16
static __device__ __forceinline__ void gload_lds16(const short* g, short* l) {
    __builtin_amdgcn_global_load_lds(
        (const __attribute__((address_space(1))) void*)g,
        (__attribute__((address_space(3))) void*)l, 16, 0, 0);
}

__device__ const float SCALEF = (float)(1.0 / 96.0);  // (M+T)^-0.5

// ---------------- K0: pre-split weights (K,Q: hi+lo; V: hi only) ----------------
__global__ __launch_bounds__(256) void k_wsplit(
    const float* __restrict__ Wk, const float* __restrict__ Wq, const float* __restrict__ Wv,
    short* __restrict__ wkh, short* __restrict__ wkl,
    short* __restrict__ wqh, short* __restrict__ wql,
    short* __restrict__ wvh)
{
    int idx = blockIdx.x * 256 + threadIdx.x;     // 3 * 32768 threads, 4 elems each
    int m = idx >> 15;
    int o4 = (idx & 32767) * 4;
    const float* W = m == 0 ? Wk : (m == 1 ? Wq : Wv);
    f32x4 v = *(const f32x4*)&W[o4];
    s16x4 hi, lo;
#pragma unroll
    for (int j = 0; j < 4; ++j) { short h, l; bfsplit(v[j], h, l); hi[j] = h; lo[j] = l; }
    if (m == 0) { *(s16x4*)&wkh[o4] = hi; *(s16x4*)&wkl[o4] = lo; }
    else if (m == 1) { *(s16x4*)&wqh[o4] = hi; *(s16x4*)&wql[o4] = lo; }
    else { *(s16x4*)&wvh[o4] = hi; }
}

// ---------------- K1: fused K,V projection (64-row s-tiles) ----------------
__global__ __launch_bounds__(256, 2) void k_proj_kv(
    const float* __restrict__ memory, const int* __restrict__ mbd,
    const int* __restrict__ bpl, const float* __restrict__ pos_table,
    const float* __restrict__ inp,
    const short* __restrict__ wkh, const short* __restrict__ wkl,
    const short* __restrict__ wvh,
    short* __restrict__ kbh, short* __restrict__ kbl,
    short* __restrict__ vTh)
{
    __shared__ __align__(16) short smA[2][64 * LDW];       // Ah, Al (10.2KB)
    __shared__ __align__(16) short smB[2][3][128 * 32];    // dbuf x {kh,kl,vh} (48KB)

    const int tid = threadIdx.x;
    const int b   = blockIdx.y;
    const int s0  = blockIdx.x * 64;
    const bool reset = (bpl[b] == 0);
    const int lane = tid & 63, wid = tid >> 6;
    const int wc = wid;                          // wave owns cols wc*32..+32
    const int fr = lane & 15, fq = lane >> 4;
    const int lrow = tid >> 3, lkq = tid & 7;

    int pixr[2];
    const float* aptr[2];
#pragma unroll
    for (int p = 0; p < 2; ++p) {
        int s = s0 + p * 32 + lrow;
        if (s < MM) {
            int d = reset ? 1 : (mbd[b * MM + s] + 1);
            pixr[p] = 31 - __clz(d);
            aptr[p] = reset ? nullptr : &memory[((size_t)b * MM + s) * EE];
        } else {
            pixr[p] = -1;
            aptr[p] = &inp[((size_t)b * TT + (s - MM)) * EE];
        }
    }

    f32x4 accK[4][2], accV[4][2];
#pragma unroll
    for (int m = 0; m < 4; ++m)
#pragma unroll
        for (int n = 0; n < 2; ++n) {
            accK[m][n] = (f32x4){0.f, 0.f, 0.f, 0.f};
            accV[m][n] = (f32x4){0.f, 0.f, 0.f, 0.f};
        }

    const int wh   = (tid >> 2);
    const int wk8  = (tid & 3) * 8;
    const int wdst = wid * 512;

    auto STAGEW = [&](int e0, int buf) {
#pragma unroll
        for (int p = 0; p < 2; ++p) {
            int h = p * 64 + wh;
            int ec = wk8 ^ ((h & 3) << 3);
            size_t g = (size_t)h * EE + e0 + ec;
            gload_lds16(&wkh[g], &smB[buf][0][p * 2048 + wdst]);
            gload_lds16(&wkl[g], &smB[buf][1][p * 2048 + wdst]);
            gload_lds16(&wvh[g], &smB[buf][2][p * 2048 + wdst]);
        }
    };
    auto LOADA = [&](int e0, f32x4 xa[2]) {
#pragma unroll
        for (int p = 0; p < 2; ++p) {
            f32x4 v = (f32x4){0.f, 0.f, 0.f, 0.f};
            if (aptr[p]) v = *(const f32x4*)&aptr[p][e0 + lkq * 4];
            if (pixr[p] >= 0) {
                f32x4 pt = *(const f32x4*)&pos_table[(size_t)pixr[p] * EE + e0 + lkq * 4];
                v[0] += pt[0]; v[1] += pt[1]; v[2] += pt[2]; v[3] += pt[3];
            }
            xa[p] = v;
        }
    };
    auto STOREA = [&](const f32x4 xa[2]) {
#pragma unroll
        for (int p = 0; p < 2; ++p) {
            int row = p * 32 + lrow;
            s16x4 hi, lo;
#pragma unroll
            for (int c = 0; c < 4; ++c) { short h, l; bfsplit(xa[p][c], h, l); hi[c] = h; lo[c] = l; }
            *(s16x4*)&smA[0][row * LDW + lkq * 4] = hi;
            *(s16x4*)&smA[1][row * LDW + lkq * 4] = lo;
        }
    };

    f32x4 xa[2];
    LOADA(0, xa);
    STOREA(xa);
    STAGEW(0, 0);
    __syncthreads();

    for (int step = 0; step < 32; ++step) {
        const int buf = step & 1;
        if (step < 31) {
            LOADA((step + 1) * BK, xa);       // reg prefetch of next A tile
            STAGEW((step + 1) * BK, buf ^ 1); // async W loads land during MFMA phase
        }

        bf16x8 ah[4], al[4];
#pragma unroll
        for (int m = 0; m < 4; ++m) {
            int r = m * 16 + fr;
            ah[m] = *(const bf16x8*)&smA[0][r * LDW + fq * 8];
            al[m] = *(const bf16x8*)&smA[1][r * LDW + fq * 8];
        }
#pragma unroll
        for (int n = 0; n < 2; ++n) {
            int c = wc * 32 + n * 16 + fr;
            int off = c * 32 + ((fq * 8) ^ ((c & 3) << 3));
            bf16x8 kh = *(const bf16x8*)&smB[buf][0][off];
            bf16x8 kl = *(const bf16x8*)&smB[buf][1][off];
            bf16x8 vh = *(const bf16x8*)&smB[buf][2][off];
#pragma unroll
            for (int m = 0; m < 4; ++m) {
                accK[m][n] = __builtin_amdgcn_mfma_f32_16x16x32_bf16(ah[m], kh, accK[m][n], 0, 0, 0);
                accK[m][n] = __builtin_amdgcn_mfma_f32_16x16x32_bf16(ah[m], kl, accK[m][n], 0, 0, 0);
                accK[m][n] = __builtin_amdgcn_mfma_f32_16x16x32_bf16(al[m], kh, accK[m][n], 0, 0, 0);
                accV[m][n] = __builtin_amdgcn_mfma_f32_16x16x32_bf16(ah[m], vh, accV[m][n], 0, 0, 0);
                accV[m][n] = __builtin_amdgcn_mfma_f32_16x16x32_bf16(al[m], vh, accV[m][n], 0, 0, 0);
            }
        }
        if (step < 31) {
            __syncthreads();     // MFMA reads done everywhere; STAGEW drained
            STOREA(xa);          // write next A tile
            __syncthreads();     // lgkm-only drain, cheap
        }
    }

    // ---- K epilogue: hi/lo planes, layout [b][s][h] ----
#pragma unroll
    for (int m = 0; m < 4; ++m) {
        int row = s0 + m * 16 + fq * 4;
#pragma unroll
        for (int n = 0; n < 2; ++n) {
            int col = wc * 32 + n * 16 + fr;
#pragma unroll
            for (int i = 0; i < 4; ++i) {
                short h, l; bfsplit(accK[m][n][i], h, l);
                size_t o = ((size_t)b * SS + row + i) * HH + col;
                kbh[o] = h; kbl[o] = l;
            }
        }
    }
    // ---- V epilogue: transpose via LDS (aliasing smB), write [b][h][s] hi plane ----
    float* tpT = (float*)smB;   // [32][68] f32 = 8.7KB
#pragma unroll
    for (int hp = 0; hp < 4; ++hp) {
        __syncthreads();
        if (wc == hp) {
#pragma unroll
            for (int m = 0; m < 4; ++m)
#pragma unroll
                for (int n = 0; n < 2; ++n) {
                    int cl = n * 16 + fr;           // local h (0..31)
                    int row = m * 16 + fq * 4;      // s-local
                    *(f32x4*)&tpT[cl * 68 + row] = accV[m][n];
                }
        }
        __syncthreads();
        for (int idx = tid; idx < 32 * 16; idx += 256) {
            int hcl = idx >> 4, s4 = (idx & 15) << 2;
            f32x4 v = *(const f32x4*)&tpT[hcl * 68 + s4];
            s16x4 hi;
#pragma unroll
            for (int j = 0; j < 4; ++j) hi[j] = (short)f2bf(v[j]);
            size_t o = ((size_t)b * HH + hp * 32 + hcl) * SS + s0 + s4;
            *(s16x4*)&vTh[o] = hi;
        }
    }
}

// ---------------- K2: Q projection (64-row t-tiles) ----------------
__global__ __launch_bounds__(256, 2) void k_proj_q(
    const float* __restrict__ inp,
    const short* __restrict__ wqh, const short* __restrict__ wql,
    short* __restrict__ qbh, short* __restrict__ qbl)
{
    __shared__ __align__(16) short smA[2][64 * LDW];
    __shared__ __align__(16) short smB[2][2][128 * 32];
    const int tid = threadIdx.x;
    const int b   = blockIdx.y;
    const int t0  = blockIdx.x * 64;
    const int lane = tid & 63, wid = tid >> 6;
    const int wc = wid;
    const int fr = lane & 15, fq = lane >> 4;
    const int lrow = tid >> 3, lkq = tid & 7;
    const int wh   = (tid >> 2);
    const int wk8  = (tid & 3) * 8;
    const int wdst = wid * 512;

    f32x4 acc[4][2];
#pragma unroll
    for (int m = 0; m < 4; ++m)
#pragma unroll
        for (int n = 0; n < 2; ++n) acc[m][n] = (f32x4){0.f, 0.f, 0.f, 0.f};

    auto STAGEWQ = [&](int e0, int buf) {
#pragma unroll
        for (int p = 0; p < 2; ++p) {
            int h = p * 64 + wh;
            int ec = wk8 ^ ((h & 3) << 3);
            size_t g = (size_t)h * EE + e0 + ec;
            gload_lds16(&wqh[g], &smB[buf][0][p * 2048 + wdst]);
            gload_lds16(&wql[g], &smB[buf][1][p * 2048 + wdst]);
        }
    };
    auto LOADA = [&](int e0, f32x4 xa[2]) {
#pragma unroll
        for (int p = 0; p < 2; ++p)
            xa[p] = *(const f32x4*)&inp[((size_t)b * TT + t0 + p * 32 + lrow) * EE + e0 + lkq * 4];
    };
    auto STOREA = [&](const f32x4 xa[2]) {
#pragma unroll
        for (int p = 0; p < 2; ++p) {
            int row = p * 32 + lrow;
            s16x4 hi, lo;
#pragma unroll
            for (int c = 0; c < 4; ++c) { short h, l; bfsplit(xa[p][c], h, l); hi[c] = h; lo[c] = l; }
            *(s16x4*)&smA[0][row * LDW + lkq * 4] = hi;
            *(s16x4*)&smA[1][row * LDW + lkq * 4] = lo;
        }
    };

    f32x4 xa[2];
    LOADA(0, xa);
    STOREA(xa);
    STAGEWQ(0, 0);
    __syncthreads();

    for (int step = 0; step < 32; ++step) {
        const int buf = step & 1;
        if (step < 31) {
            LOADA((step + 1) * BK, xa);
            STAGEWQ((step + 1) * BK, buf ^ 1);
        }
        bf16x8 ah[4], al[4];
#pragma unroll
        for (int m = 0; m < 4; ++m) {
            int r = m * 16 + fr;
            ah[m] = *(const bf16x8*)&smA[0][r * LDW + fq * 8];
            al[m] = *(const bf16x8*)&smA[1][r * LDW + fq * 8];
        }
#pragma unroll
        for (int n = 0; n < 2; ++n) {
            int c = wc * 32 + n * 16 + fr;
            int off = c * 32 + ((fq * 8) ^ ((c & 3) << 3));
            bf16x8 bh = *(const bf16x8*)&smB[buf][0][off];
            bf16x8 bl = *(const bf16x8*)&smB[buf][1][off];
#pragma unroll
            for (int m = 0; m < 4; ++m) {
                acc[m][n] = __builtin_amdgcn_mfma_f32_16x16x32_bf16(ah[m], bh, acc[m][n], 0, 0, 0);
                acc[m][n] = __builtin_amdgcn_mfma_f32_16x16x32_bf16(ah[m], bl, acc[m][n], 0, 0, 0);
                acc[m][n] = __builtin_amdgcn_mfma_f32_16x16x32_bf16(al[m], bh, acc[m][n], 0, 0, 0);
            }
        }
        if (step < 31) {
            __syncthreads();
            STOREA(xa);
            __syncthreads();
        }
    }
#pragma unroll
    for (int m = 0; m < 4; ++m) {
        int row = t0 + m * 16 + fq * 4;
#pragma unroll
        for (int n = 0; n < 2; ++n) {
            int col = wc * 32 + n * 16 + fr;
#pragma unroll
            for (int i = 0; i < 4; ++i) {
                short h, l; bfsplit(acc[m][n][i], h, l);
                size_t o = ((size_t)b * TT + row + i) * HH + col;
                qbh[o] = h; qbl[o] = l;
            }
        }
    }
}

// ---------------- shared attn helpers (MUST be identical in k_rowmax / k_attn) ----
// K tile [64 s][128 h] hi/lo via global_load_lds, swizzle applied on SOURCE addr;
// LDS content[s][col] = global[s][col ^ ((s&7)<<3)] — matches qk_mfma4's read XOR.
__device__ __forceinline__ void stage_k64_async(const short* __restrict__ srcH,
                                                const short* __restrict__ srcL,
                                                size_t rowBase, int tid,
                                                short* sh, short* sl)
{
#pragma unroll
    for (int c2 = 0; c2 < 4; ++c2) {
        int srow = c2 * 16 + (tid >> 4);
        int scol = ((tid & 15) * 8) ^ ((srow & 7) << 3);
        size_t g = (rowBase + srow) * HH + scol;
        gload_lds16(&srcH[g], &sh[c2 * 2048 + (tid >> 6) * 512]);
        gload_lds16(&srcL[g], &sl[c2 * 2048 + (tid >> 6) * 512]);
    }
}

__device__ __forceinline__ void load_qfrags(const short* __restrict__ qH, const short* __restrict__ qL,
                                            size_t rowIx, int fq, bf16x8 qh[4], bf16x8 ql[4])
{
    size_t base = rowIx * HH + fq * 8;
#pragma unroll
    for (int k = 0; k < 4; ++k) {
        qh[k] = *(const bf16x8*)&qH[base + k * 32];
        ql[k] = *(const bf16x8*)&qL[base + k * 32];
    }
}

__device__ __forceinline__ void qk_mfma4(const bf16x8 qh[4], const bf16x8 ql[4],
                                         const short* sh, const short* sl,
                                         int fr, int fq, f32x4 acc[4])
{
#pragma unroll
    for (int n = 0; n < 4; ++n) {
        int sc = n * 16 + fr;
        int ro = sc * 128, msk = (sc & 7) << 3;
#pragma unroll
        for (int k = 0; k < 4; ++k) {
            int off = ro + ((k * 32 + fq * 8) ^ msk);
            bf16x8 bh = *(const bf16x8*)&sh[off];
            bf16x8 bl = *(const bf16x8*)&sl[off];
            acc[n] = __builtin_amdgcn_mfma_f32_16x16x32_bf16(ql[k], bh, acc[n], 0, 0, 0);
            acc[n] = __builtin_amdgcn_mfma_f32_16x16x32_bf16(qh[k], bl, acc[n], 0, 0, 0);
            acc[n] = __builtin_amdgcn_mfma_f32_16x16x32_bf16(qh[k], bh, acc[n], 0, 0, 0);
        }
    }
}

// ---------------- K3: rowmax of (qk*scale)^2 via MFMA ----------------
__global__ __launch_bounds__(256) void k_rowmax(
    const short* __restrict__ qbh, const short* __restrict__ qbl,
    const short* __restrict__ kbh, const short* __restrict__ kbl,
    float* __restrict__ rowmax)
{
    __shared__ short Ksh[64 * 128], Ksl[64 * 128];
    const int tid = threadIdx.x, lane = tid & 63, wloc = tid >> 6;
    const int fr = lane & 15, fq = lane >> 4;
    const int split = blockIdx.x, t0 = blockIdx.y * 64, b = blockIdx.z;

    bf16x8 qh[4], ql[4];
    load_qfrags(qbh, qbl, (size_t)b * TT + t0 + wloc * 16 + fr, fq, qh, ql);

    float rm[4] = {0.f, 0.f, 0.f, 0.f};
    const int sBeg = split * SCHUNK;
    for (int st = sBeg; st < sBeg + SCHUNK; st += 64) {
        __syncthreads();
        stage_k64_async(kbh, kbl, (size_t)b * SS + st, tid, Ksh, Ksl);
        __syncthreads();
        f32x4 acc[4];
#pragma unroll
        for (int n = 0; n < 4; ++n) acc[n] = (f32x4){0.f, 0.f, 0.f, 0.f};
        qk_mfma4(qh, ql, Ksh, Ksl, fr, fq, acc);
#pragma unroll
        for (int n = 0; n < 4; ++n)
#pragma unroll
            for (int i = 0; i < 4; ++i) {
                float w = acc[n][i] * SCALEF;
                rm[i] = fmaxf(rm[i], w * w);
            }
    }
#pragma unroll
    for (int d = 1; d < 16; d <<= 1)
#pragma unroll
        for (int i = 0; i < 4; ++i)
            rm[i] = fmaxf(rm[i], __shfl_xor(rm[i], d, 64));
    if (fr == 0)
#pragma unroll
        for (int i = 0; i < 4; ++i)
            atomicMax((int*)&rowmax[b * TT + t0 + wloc * 16 + fq * 4 + i], __float_as_int(rm[i]));
}

// ---------------- K4: attention (wei, out, colsum-part, qt_loss) via MFMA ----------------
__global__ __launch_bounds__(256) void k_attn(
    const short* __restrict__ qbh, const short* __restrict__ qbl,
    const short* __restrict__ kbh, const short* __restrict__ kbl,
    const short* __restrict__ vTh,
    const float* __restrict__ rowmax,
    float* __restrict__ outAcc, float* __restrict__ cpart, float* __restrict__ qtloss)
{
    __shared__ short Ksh[64 * 128], Ksl[64 * 128];   // K tile
    __shared__ short Vsh[128 * 64];                   // V^T tile (hi only)
    __shared__ short Ph[64 * 64];
    __shared__ float csLDS[SCHUNK];
    __shared__ float qred[256];
    const int tid = threadIdx.x, lane = tid & 63, wloc = tid >> 6;
    const int fr = lane & 15, fq = lane >> 4;
    const int split = blockIdx.x, t0 = blockIdx.y * 64, b = blockIdx.z;

    for (int i = tid; i < SCHUNK; i += 256) csLDS[i] = 0.f;

    bf16x8 qh[4], ql[4];
    load_qfrags(qbh, qbl, (size_t)b * TT + t0 + wloc * 16 + fr, fq, qh, ql);

    float inv[4];
#pragma unroll
    for (int i = 0; i < 4; ++i)
        inv[i] = 1.0f / rowmax[b * TT + t0 + wloc * 16 + fq * 4 + i];

    f32x4 oacc[8];
#pragma unroll
    for (int n = 0; n < 8; ++n) oacc[n] = (f32x4){0.f, 0.f, 0.f, 0.f};
    float qtp = 0.f;

    const int sBeg = split * SCHUNK;
    for (int st = sBeg; st < sBeg + SCHUNK; st += 64) {
        __syncthreads();    // previous PV done with Vsh/Ph, previous QK done with K
        // stage K (hi/lo, swizzled source) + V^T (hi, swizzled source) together
        stage_k64_async(kbh, kbl, (size_t)b * SS + st, tid, Ksh, Ksl);
#pragma unroll
        for (int c2 = 0; c2 < 4; ++c2) {
            int h = c2 * 32 + (tid >> 3);
            int sc = ((tid & 7) * 8) ^ ((h & 7) << 3);
            size_t g = ((size_t)b * HH + h) * SS + st + sc;
            gload_lds16(&vTh[g], &Vsh[c2 * 2048 + (tid >> 6) * 512]);
        }
        __syncthreads();    // vmcnt drain: K+V in LDS

        f32x4 acc[4];
#pragma unroll
        for (int n = 0; n < 4; ++n) acc[n] = (f32x4){0.f, 0.f, 0.f, 0.f};
        qk_mfma4(qh, ql, Ksh, Ksl, fr, fq, acc);

#pragma unroll
        for (int n = 0; n < 4; ++n) {
            float cp = 0.f;
#pragma unroll
            for (int i = 0; i < 4; ++i) {
                float w = acc[n][i] * SCALEF;
                float w2 = w * w;
                float wei = w2 * inv[i];
                qtp += __logf(wei + 1e-4f);
                cp += wei;
                int r = wloc * 16 + fq * 4 + i;
                int sw = (n * 16 + fr) ^ ((r & 7) << 3);
                Ph[r * 64 + sw] = (short)f2bf(wei);
            }
            cp += __shfl_xor(cp, 16, 64);
            cp += __shfl_xor(cp, 32, 64);
            if (fq == 0) atomicAdd(&csLDS[st - sBeg + n * 16 + fr], cp);
        }
        __syncthreads();    // Ph visible
        // PV (P hi-only x V hi-only)
        {
            int rA = wloc * 16 + fr;
#pragma unroll
            for (int k = 0; k < 2; ++k) {
                int offA = rA * 64 + ((k * 32 + fq * 8) ^ ((rA & 7) << 3));
                bf16x8 ph = *(const bf16x8*)&Ph[offA];
#pragma unroll
                for (int n = 0; n < 8; ++n) {
                    int hc = n * 16 + fr;
                    int offB = hc * 64 + ((k * 32 + fq * 8) ^ ((hc & 7) << 3));
                    bf16x8 vh = *(const bf16x8*)&Vsh[offB];
                    oacc[n] = __builtin_amdgcn_mfma_f32_16x16x32_bf16(ph, vh, oacc[n], 0, 0, 0);
                }
            }
        }
    }

#pragma unroll
    for (int n = 0; n < 8; ++n)
#pragma unroll
        for (int i = 0; i < 4; ++i)
            atomicAdd(&outAcc[((size_t)b * TT + t0 + wloc * 16 + fq * 4 + i) * HH + n * 16 + fr],
                      oacc[n][i]);

    qred[tid] = qtp;
    __syncthreads();
    for (int off = 128; off; off >>= 1) {
        if (tid < off) qred[tid] += qred[tid + off];
        __syncthreads();
    }
    if (tid == 0) atomicAdd(qtloss, qred[0]);

    const int tt = blockIdx.y;
    for (int s = tid; s < SCHUNK; s += 256)
        cpart[((size_t)(b * 16 + tt)) * SS + sBeg + s] = csLDS[s];
}

// ---------------- K5: rank + sortable keys (deterministic colsum reduce) ----------------
__global__ __launch_bounds__(256) void k_rank(
    const float* __restrict__ cpart, const float* __restrict__ mrank,
    unsigned long long* __restrict__ keys, float* __restrict__ csum)
{
    const int b = blockIdx.x, tid = threadIdx.x;
    __shared__ float red[256];
    float p = 0.f;
    for (int s = tid; s < SS; s += 256) {
        float cs = 0.f;
#pragma unroll
        for (int tt = 0; tt < 16; ++tt) cs += cpart[((size_t)(b * 16 + tt)) * SS + s];
        csum[b * SS + s] = cs;
        p += cs;
    }
    red[tid] = p;
    __syncthreads();
    for (int off = 128; off; off >>= 1) {
        if (tid < off) red[tid] += red[tid + off];
        __syncthreads();
    }
    float mean = red[0] / (float)SS;
    for (int m = tid; m < MM; m += 256) {
        float rank = ((mrank[b * MM + m] + csum[b * SS + m] / mean) - 1.0f) - 0.01f;
        keys[b * MM + m] = ((unsigned long long)(unsigned)(~f2ord(rank)) << 32) | (unsigned)m;
    }
}

// ---------------- K6: in-LDS bitonic sort ----------------
__global__ __launch_bounds__(1024) void k_sort(unsigned long long* __restrict__ keys)
{
    __shared__ unsigned long long a[MM];
    const int b = blockIdx.x, tid = threadIdx.x;
    for (int i = tid; i < MM; i += 1024) a[i] = keys[(size_t)b * MM + i];
    __syncthreads();
    for (int k = 2; k <= MM; k <<= 1) {
        for (int j = k >> 1; j > 0; j >>= 1) {
            for (int i = tid; i < MM; i += 1024) {
                int l = i ^ j;
                if (l > i) {
                    unsigned long long x = a[i], y = a[l];
                    bool up = ((i & k) == 0);
                    if ((x > y) == up) { a[i] = y; a[l] = x; }
                }
            }
            __syncthreads();
        }
    }
    for (int i = tid; i < MM; i += 1024) keys[(size_t)b * MM + i] = a[i];
}

// ---------------- K7: scatter sorted memory / dist / rank ----------------
__global__ __launch_bounds__(256) void k_scatter(
    const float* __restrict__ memory, const int* __restrict__ mbd,
    const int* __restrict__ bpl, const float* __restrict__ inp,
    const unsigned long long* __restrict__ keys,
    float* __restrict__ nmem, float* __restrict__ ndist, float* __restrict__ nrank)
{
    const int blk = blockIdx.x;
    const int b = blk >> 10;
    const int p0 = (blk & 1023) * 8;
    const bool reset = (bpl[b] == 0);
    const int tid = threadIdx.x;
    const f32x4 zero = (f32x4){0.f, 0.f, 0.f, 0.f};
    for (int r = 0; r < 8; ++r) {
        int p = p0 + r;
        float* drow = &nmem[((size_t)b * MM + p) * EE];
        if (p < RKEEP) {
            unsigned long long key = keys[(size_t)b * MM + p];
            int src = (int)(unsigned)(key & 0xFFFFFFFFu);
            if (reset) {
                *(f32x4*)&drow[tid * 4] = zero;
            } else {
                const float* srow = &memory[((size_t)b * MM + src) * EE];
                *(f32x4*)&drow[tid * 4] = *(const f32x4*)&srow[tid * 4];
            }
            if (tid == 0) {
                ndist[b * MM + p] = reset ? 1.0f : (float)(mbd[b * MM + src] + 1);
                nrank[b * MM + p] = ord2f(~(unsigned)(key >> 32));
            }
        } else {
            int irow = p - RKEEP;
            const float* srow = &inp[((size_t)b * TT + irow) * EE];
            *(f32x4*)&drow[tid * 4] = *(const f32x4*)&srow[tid * 4];
            if (tid == 0) { ndist[b * MM + p] = 0.f; nrank[b * MM + p] = 1.0f; }
        }
    }
}

// ---------------- launcher ----------------
extern "C" void kernel_launch(void* const* d_in, const int* in_sizes, int n_in,
                              void* d_out, int out_size, void* d_ws, size_t ws_size,
                              hipStream_t stream)
{
    const int*   bpl    = (const int*)d_in[0];
    const float* inp    = (const float*)d_in[1];
    const float* memory = (const float*)d_in[2];
    const int*   mbd    = (const int*)d_in[3];
    const float* mrank  = (const float*)d_in[4];
    const float* pos    = (const float*)d_in[5];
    const float* Wk     = (const float*)d_in[6];
    const float* Wq     = (const float*)d_in[7];
    const float* Wv     = (const float*)d_in[8];

    float* out   = (float*)d_out;                    // [B,T,H]
    float* qtl   = out + (size_t)BB * TT * HH;       // scalar
    float* nmem  = qtl + 1;                          // [B,M,E]
    float* ndist = nmem + (size_t)BB * MM * EE;      // [B,M]
    float* nrank = ndist + (size_t)BB * MM;          // [B,M]

    char* w = (char*)d_ws;
    short* qbh = (short*)w; w += (size_t)BB * TT * HH * 2;
    short* qbl = (short*)w; w += (size_t)BB * TT * HH * 2;
    short* kbh = (short*)w; w += (size_t)BB * SS * HH * 2;
    short* kbl = (short*)w; w += (size_t)BB * SS * HH * 2;
    short* vTh = (short*)w; w += (size_t)BB * HH * SS * 2;
    float* rmax = (float*)w; w += (size_t)BB * TT * 4;
    float* csum = (float*)w; w += (size_t)BB * SS * 4;
    float* cpart = (float*)w; w += (size_t)BB * 16 * SS * 4;
    unsigned long long* keys = (unsigned long long*)w; w += (size_t)BB * MM * 8;
    short* wkh = (short*)w; w += (size_t)HH * EE * 2;
    short* wkl = (short*)w; w += (size_t)HH * EE * 2;
    short* wqh = (short*)w; w += (size_t)HH * EE * 2;
    short* wql = (short*)w; w += (size_t)HH * EE * 2;
    short* wvh = (short*)w; w += (size_t)HH * EE * 2;
    if ((size_t)(w - (char*)d_ws) > ws_size) return;

    hipMemsetAsync(d_out, 0, ((size_t)BB * TT * HH + 1) * 4, stream);
    hipMemsetAsync(rmax, 0, (size_t)BB * TT * 4, stream);

    k_wsplit <<<384, 256, 0, stream>>>(Wk, Wq, Wv, wkh, wkl, wqh, wql, wvh);
    k_proj_kv<<<dim3(SS / 64, BB), 256, 0, stream>>>(memory, mbd, bpl, pos, inp,
                                                     wkh, wkl, wvh,
                                                     kbh, kbl, vTh);
    k_proj_q <<<dim3(TT / 64, BB), 256, 0, stream>>>(inp, wqh, wql, qbh, qbl);
    k_rowmax <<<dim3(NSPLIT, TT / 64, BB), 256, 0, stream>>>(qbh, qbl, kbh, kbl, rmax);
    k_attn   <<<dim3(NSPLIT, TT / 64, BB), 256, 0, stream>>>(qbh, qbl, kbh, kbl, vTh,
                                                             rmax, out, cpart, qtl);
    k_rank   <<<BB, 256, 0, stream>>>(cpart, mrank, keys, csum);
    k_sort   <<<BB, 1024, 0, stream>>>(keys);
    k_scatter<<<BB * (MM / 8), 256, 0, stream>>>(memory, mbd, bpl, inp, keys, nmem, ndist, nrank);
}